// Round 2
// baseline (379.062 us; speedup 1.0000x reference)
//
#include <hip/hip_runtime.h>
#include <hip/hip_bf16.h>

typedef __bf16 bf16x8 __attribute__((ext_vector_type(8)));
typedef float f32x4 __attribute__((ext_vector_type(4)));

#define BS   8192   // B*S rows
#define Hd   1024
#define LSd  2048
#define Md   64

static __device__ __forceinline__ float bfu2f(unsigned short u) {
  return __uint_as_float(((unsigned int)u) << 16);
}
static __device__ __forceinline__ __hip_bfloat16 f2bf(float f) { return __float2bfloat16(f); }

// ======================= prep kernels =======================

__global__ __launch_bounds__(256) void conv_bf16_kernel(const float* __restrict__ src,
    __hip_bfloat16* __restrict__ dst, int n) {
  int i = (blockIdx.x * 256 + threadIdx.x) * 4;
  if (i + 3 < n) {
    float4 f = *(const float4*)(src + i);
    ushort4 o;
    o.x = (unsigned short)(__bfloat16_as_ushort(f2bf(f.x)));
    o.y = (unsigned short)(__bfloat16_as_ushort(f2bf(f.y)));
    o.z = (unsigned short)(__bfloat16_as_ushort(f2bf(f.z)));
    o.w = (unsigned short)(__bfloat16_as_ushort(f2bf(f.w)));
    *(ushort4*)(dst + i) = o;
  }
}

// Wcat_t[512][1024]: n=0 decay, 1..128 key, 129..256 value, 257..320 ql, 321..384 qr, rest 0
__global__ __launch_bounds__(256) void prep_wcat_kernel(const float* __restrict__ Wd,
    const float* __restrict__ Wk, const float* __restrict__ Wv,
    const float* __restrict__ Wql, const float* __restrict__ Wqr,
    __hip_bfloat16* __restrict__ out) {
  int i = blockIdx.x * 256 + threadIdx.x;   // 512*1024 total
  int n = i >> 10, h = i & 1023;
  float v = 0.f;
  if (n == 0)        v = Wd[h];
  else if (n < 129)  v = Wk[h * 128 + (n - 1)];
  else if (n < 257)  v = Wv[h * 128 + (n - 129)];
  else if (n < 321)  v = Wql[h * 64 + (n - 257)];
  else if (n < 385)  v = Wqr[h * 64 + (n - 321)];
  out[i] = f2bf(v);
}

// dst[(c + c_off)][r] = (bf16) src[r][c];  src is R x C f32, dst leading dim = R
__global__ __launch_bounds__(256) void transpose_conv_kernel(const float* __restrict__ src,
    __hip_bfloat16* __restrict__ dst, int R, int C, int c_off) {
  __shared__ float tile[32][33];
  int bc = blockIdx.x * 32, br = blockIdx.y * 32;
  int tx = threadIdx.x & 31, ty = threadIdx.x >> 5;   // 32 x 8
  #pragma unroll
  for (int i = 0; i < 32; i += 8)
    tile[ty + i][tx] = src[(size_t)(br + ty + i) * C + bc + tx];
  __syncthreads();
  #pragma unroll
  for (int i = 0; i < 32; i += 8)
    dst[(size_t)(bc + c_off + ty + i) * R + br + tx] = f2bf(tile[tx][ty + i]);
}

// ======================= GEMM core =======================
// 128x128 tile, BK=32, 256 threads = 4 waves (2x2 of 64x64), mfma 16x16x32 bf16.
// LDS tiles are FRAGMENT-MAJOR: chunk ri (16 rows x 32 cols) holds element
// (row=ri*16+fr, k-chunk q of 8) at ri*512 + (q*16+fr)*8 bf16. A wave's MFMA
// fragment read is then base + lane*16 bytes (conflict-free ds_read_b128), and
// global_load_lds (wave-uniform base + lane*16) stages it directly.

static __device__ __forceinline__ void stage_async(const __hip_bfloat16* __restrict__ src, int ld,
    __hip_bfloat16* __restrict__ dst, int wave, int lane) {
  int fr = lane & 15, ch = lane >> 4;
  #pragma unroll
  for (int it = 0; it < 2; ++it) {
    int ri = wave * 2 + it;
    int row = ri * 16 + fr;
    __builtin_amdgcn_global_load_lds(
        (const __attribute__((address_space(1))) void*)(src + (size_t)row * ld + ch * 8),
        (__attribute__((address_space(3))) void*)(dst + ri * 512),
        16, 0, 0);
  }
}

static __device__ __forceinline__ void mfma_single(const __hip_bfloat16* sA, const __hip_bfloat16* sB,
    int wm16, int wn16, int lane, f32x4 acc[4][4]) {
  bf16x8 af[4], bg[4];
  #pragma unroll
  for (int i = 0; i < 4; ++i) af[i] = *(const bf16x8*)(sA + (wm16 + i) * 512 + lane * 8);
  #pragma unroll
  for (int j = 0; j < 4; ++j) bg[j] = *(const bf16x8*)(sB + (wn16 + j) * 512 + lane * 8);
  #pragma unroll
  for (int i = 0; i < 4; ++i)
    #pragma unroll
    for (int j = 0; j < 4; ++j)
      acc[i][j] = __builtin_amdgcn_mfma_f32_16x16x32_bf16(af[i], bg[j], acc[i][j], 0, 0, 0);
}

static __device__ __forceinline__ void mfma_dual(const __hip_bfloat16* sA,
    const __hip_bfloat16* sBu, const __hip_bfloat16* sBg,
    int wm16, int wn16, int lane, f32x4 accu[4][4], f32x4 accg[4][4]) {
  bf16x8 af[4], bu[4], bg[4];
  #pragma unroll
  for (int i = 0; i < 4; ++i) af[i] = *(const bf16x8*)(sA + (wm16 + i) * 512 + lane * 8);
  #pragma unroll
  for (int j = 0; j < 4; ++j) bu[j] = *(const bf16x8*)(sBu + (wn16 + j) * 512 + lane * 8);
  #pragma unroll
  for (int j = 0; j < 4; ++j) bg[j] = *(const bf16x8*)(sBg + (wn16 + j) * 512 + lane * 8);
  #pragma unroll
  for (int i = 0; i < 4; ++i)
    #pragma unroll
    for (int j = 0; j < 4; ++j) {
      accu[i][j] = __builtin_amdgcn_mfma_f32_16x16x32_bf16(af[i], bu[j], accu[i][j], 0, 0, 0);
      accg[i][j] = __builtin_amdgcn_mfma_f32_16x16x32_bf16(af[i], bg[j], accg[i][j], 0, 0, 0);
    }
}

// proj = x_bf @ Wcat_t^T : C[8192][512] f32
__global__ __launch_bounds__(256, 2) void gemm_proj_kernel(const __hip_bfloat16* __restrict__ A,
    const __hip_bfloat16* __restrict__ Bt, float* __restrict__ C) {
  __shared__ __align__(16) __hip_bfloat16 sA[128 * 32];
  __shared__ __align__(16) __hip_bfloat16 sB[128 * 32];
  int tid = threadIdx.x, nb = blockIdx.x, mb = blockIdx.y;
  int wave = tid >> 6, lane = tid & 63;
  int wm16 = (wave >> 1) * 4, wn16 = (wave & 1) * 4;
  int fr = lane & 15, q4 = (lane >> 4) * 4;
  f32x4 acc[4][4] = {};
  const __hip_bfloat16* Atile = A + (size_t)mb * 128 * Hd;
  const __hip_bfloat16* Btile = Bt + (size_t)nb * 128 * Hd;
  for (int kt = 0; kt < Hd; kt += 32) {
    __syncthreads();
    stage_async(Atile + kt, Hd, sA, wave, lane);
    stage_async(Btile + kt, Hd, sB, wave, lane);
    __syncthreads();
    mfma_single(sA, sB, wm16, wn16, lane, acc);
  }
  #pragma unroll
  for (int i = 0; i < 4; ++i)
    #pragma unroll
    for (int j = 0; j < 4; ++j) {
      int row = mb * 128 + (wm16 + i) * 16 + q4;
      int col = nb * 128 + (wn16 + j) * 16 + fr;
      #pragma unroll
      for (int rg = 0; rg < 4; ++rg)
        C[(size_t)(row + rg) * 512 + col] = acc[i][j][rg];
    }
}

// h = (x@W_up) * silu(x@W_gate), bf16 out, dual accumulators sharing A tile
__global__ __launch_bounds__(256, 2) void gemm_upgate_kernel(const __hip_bfloat16* __restrict__ A,
    const __hip_bfloat16* __restrict__ Bt, __hip_bfloat16* __restrict__ hout) {
  __shared__ __align__(16) __hip_bfloat16 sA[128 * 32];
  __shared__ __align__(16) __hip_bfloat16 sBu[128 * 32];
  __shared__ __align__(16) __hip_bfloat16 sBg[128 * 32];
  int tid = threadIdx.x, nb = blockIdx.x, mb = blockIdx.y;
  int wave = tid >> 6, lane = tid & 63;
  int wm16 = (wave >> 1) * 4, wn16 = (wave & 1) * 4;
  int fr = lane & 15, q4 = (lane >> 4) * 4;
  f32x4 accu[4][4] = {}, accg[4][4] = {};
  const __hip_bfloat16* Atile = A + (size_t)mb * 128 * Hd;
  const __hip_bfloat16* Bu = Bt + (size_t)(nb * 128) * Hd;
  const __hip_bfloat16* Bg = Bt + (size_t)(2048 + nb * 128) * Hd;
  for (int kt = 0; kt < Hd; kt += 32) {
    __syncthreads();
    stage_async(Atile + kt, Hd, sA, wave, lane);
    stage_async(Bu + kt, Hd, sBu, wave, lane);
    stage_async(Bg + kt, Hd, sBg, wave, lane);
    __syncthreads();
    mfma_dual(sA, sBu, sBg, wm16, wn16, lane, accu, accg);
  }
  #pragma unroll
  for (int i = 0; i < 4; ++i)
    #pragma unroll
    for (int j = 0; j < 4; ++j) {
      int col = nb * 128 + (wn16 + j) * 16 + fr;
      #pragma unroll
      for (int rg = 0; rg < 4; ++rg) {
        int row = mb * 128 + (wm16 + i) * 16 + q4 + rg;
        float u = accu[i][j][rg], g = accg[i][j][rg];
        float hv = u * g / (1.f + __expf(-g));
        hout[(size_t)row * LSd + col] = f2bf(hv);
      }
    }
}

// out = h@Wdown_t^T + Rd@Wrec_t^T  (K = 2048 then 64), f32 out
__global__ __launch_bounds__(256, 2) void gemm_final_kernel(const __hip_bfloat16* __restrict__ A,
    const __hip_bfloat16* __restrict__ Bt, const __hip_bfloat16* __restrict__ A2,
    const __hip_bfloat16* __restrict__ B2t, float* __restrict__ C) {
  __shared__ __align__(16) __hip_bfloat16 sA[128 * 32];
  __shared__ __align__(16) __hip_bfloat16 sB[128 * 32];
  int tid = threadIdx.x, nb = blockIdx.x, mb = blockIdx.y;
  int wave = tid >> 6, lane = tid & 63;
  int wm16 = (wave >> 1) * 4, wn16 = (wave & 1) * 4;
  int fr = lane & 15, q4 = (lane >> 4) * 4;
  f32x4 acc[4][4] = {};
  const __hip_bfloat16* Atile = A + (size_t)mb * 128 * LSd;
  const __hip_bfloat16* Btile = Bt + (size_t)nb * 128 * LSd;
  for (int kt = 0; kt < LSd; kt += 32) {
    __syncthreads();
    stage_async(Atile + kt, LSd, sA, wave, lane);
    stage_async(Btile + kt, LSd, sB, wave, lane);
    __syncthreads();
    mfma_single(sA, sB, wm16, wn16, lane, acc);
  }
  const __hip_bfloat16* A2t = A2 + (size_t)mb * 128 * Md;
  const __hip_bfloat16* B2tile = B2t + (size_t)nb * 128 * Md;
  for (int kt = 0; kt < Md; kt += 32) {
    __syncthreads();
    stage_async(A2t + kt, Md, sA, wave, lane);
    stage_async(B2tile + kt, Md, sB, wave, lane);
    __syncthreads();
    mfma_single(sA, sB, wm16, wn16, lane, acc);
  }
  #pragma unroll
  for (int i = 0; i < 4; ++i)
    #pragma unroll
    for (int j = 0; j < 4; ++j) {
      int row = mb * 128 + (wm16 + i) * 16 + q4;
      int col = nb * 128 + (wn16 + j) * 16 + fr;
      #pragma unroll
      for (int rg = 0; rg < 4; ++rg)
        C[(size_t)(row + rg) * Hd + col] = acc[i][j][rg];
    }
}

// ======================= recurrent (chunked gated linear attention) =======================
// chunk C=64. proj row layout: [0]=z_decay, [1..129)=key(r*64+m), [129..257)=value, [257..321)=ql, [321..385)=qr

__global__ __launch_bounds__(256) void scan_chunk_kernel(const float* __restrict__ proj,
    float* __restrict__ Lam, float* __restrict__ udv, float* __restrict__ alpha,
    float* __restrict__ dS) {
  int bc = blockIdx.x, t0 = bc * 64, tid = threadIdx.x;
  __shared__ float d_s[64], ld_s[64], Lam_s[64], u_s[64];
  __shared__ __align__(16) __hip_bfloat16 k_s[128 * 64];
  __shared__ __align__(16) __hip_bfloat16 v_s[128 * 64];
  if (tid < 64) {
    float z = proj[(size_t)(t0 + tid) * 512];
    float dd = 1.f / (1.f + __expf(-z));
    float l = (z >= 0.f) ? -log1pf(__expf(-z)) : (z - log1pf(__expf(z)));
    d_s[tid] = dd; ld_s[tid] = l;
  }
  __syncthreads();
  if (tid == 0) {
    float s = 0.f;
    for (int j = 0; j < 64; ++j) { s += ld_s[j]; Lam_s[j] = s; }
  }
  __syncthreads();
  float Lend = Lam_s[63];
  if (tid < 64) {
    u_s[tid] = (1.f - d_s[tid]) * __expf(Lend - Lam_s[tid]) * 0.5f;  // includes 1/R
    Lam[t0 + tid] = Lam_s[tid];
    udv[t0 + tid] = (1.f - d_s[tid]) * 0.5f;                          // includes 1/R
  }
  if (tid == 0) alpha[bc] = __expf(Lend);
  __syncthreads();
  for (int i = tid; i < 128 * 64; i += 256) {
    int jr = i >> 6, m = i & 63, j = jr >> 1, r = jr & 1;
    const float* rowp = proj + (size_t)(t0 + j) * 512;
    k_s[i] = f2bf(u_s[j] * rowp[1 + r * 64 + m]);
    v_s[i] = f2bf(rowp[129 + r * 64 + m]);
  }
  __syncthreads();
  int m0 = (tid & 15) * 4, n0 = (tid >> 4) * 4;
  float acc[4][4] = {{0.f}};
  for (int jr = 0; jr < 128; ++jr) {
    ushort4 ku = *(const ushort4*)&k_s[jr * 64 + m0];
    ushort4 vu = *(const ushort4*)&v_s[jr * 64 + n0];
    float k0 = bfu2f(ku.x), k1 = bfu2f(ku.y), k2 = bfu2f(ku.z), k3 = bfu2f(ku.w);
    float v0 = bfu2f(vu.x), v1 = bfu2f(vu.y), v2 = bfu2f(vu.z), v3 = bfu2f(vu.w);
    acc[0][0] += k0 * v0; acc[0][1] += k0 * v1; acc[0][2] += k0 * v2; acc[0][3] += k0 * v3;
    acc[1][0] += k1 * v0; acc[1][1] += k1 * v1; acc[1][2] += k1 * v2; acc[1][3] += k1 * v3;
    acc[2][0] += k2 * v0; acc[2][1] += k2 * v1; acc[2][2] += k2 * v2; acc[2][3] += k2 * v3;
    acc[3][0] += k3 * v0; acc[3][1] += k3 * v1; acc[3][2] += k3 * v2; acc[3][3] += k3 * v3;
  }
  float* outp = dS + (size_t)bc * 4096;
  #pragma unroll
  for (int a = 0; a < 4; ++a)
    #pragma unroll
    for (int b2 = 0; b2 < 4; ++b2)
      outp[(m0 + a) * 64 + (n0 + b2)] = acc[a][b2];
}

__global__ __launch_bounds__(256) void scan_cross_kernel(const float* __restrict__ dS,
    const float* __restrict__ alpha, const float* __restrict__ init_state,
    float* __restrict__ Sin) {
  int idx = blockIdx.x * 256 + threadIdx.x;   // 4 batches * 4096 elems
  int b = idx >> 12, e = idx & 4095;
  float s = init_state[e];
  for (int c = 0; c < 32; ++c) {
    int bc = b * 32 + c;
    Sin[(size_t)bc * 4096 + e] = s;
    s = alpha[bc] * s + dS[(size_t)bc * 4096 + e];
  }
}

#define QLD 68   // padded leading dim for ql tile (keeps 8B alignment, breaks bank stride)

__global__ __launch_bounds__(256) void scan_read_kernel(const float* __restrict__ proj,
    const float* __restrict__ Lam, const float* __restrict__ udv,
    const float* __restrict__ Sin, __hip_bfloat16* __restrict__ Rd) {
  int bc = blockIdx.x, t0 = bc * 64, tid = threadIdx.x;
  __shared__ __align__(16) __hip_bfloat16 ql_s[64 * QLD];
  __shared__ __align__(16) __hip_bfloat16 kv_s[128 * 64];   // K then V
  __shared__ __align__(16) __hip_bfloat16 S_s[64 * 64];
  __shared__ __align__(16) __hip_bfloat16 P_s[128 * 64];    // [jr][t]
  __shared__ float Lam_s[64], ud_s[64], eL_s[64];
  for (int i = tid; i < 64 * 64; i += 256) {
    int t = i >> 6, m = i & 63;
    ql_s[t * QLD + m] = f2bf(proj[(size_t)(t0 + t) * 512 + 257 + m]);
    S_s[i] = f2bf(Sin[(size_t)bc * 4096 + i]);
  }
  for (int i = tid; i < 128 * 64; i += 256) {
    int jr = i >> 6, m = i & 63, j = jr >> 1, r = jr & 1;
    kv_s[i] = f2bf(proj[(size_t)(t0 + j) * 512 + 1 + r * 64 + m]);
  }
  if (tid < 64) {
    float L = Lam[t0 + tid];
    Lam_s[tid] = L; ud_s[tid] = udv[t0 + tid]; eL_s[tid] = __expf(L);
  }
  __syncthreads();
  int tr = (tid & 15) * 4, n0 = (tid >> 4) * 4;
  float acc[4][4] = {{0.f}};
  // cross term: e^{Lam_t} * (ql_t @ S_in)
  for (int mb4 = 0; mb4 < 64; mb4 += 4) {
    float sm[4][4];
    #pragma unroll
    for (int mm = 0; mm < 4; ++mm) {
      ushort4 sv = *(const ushort4*)&S_s[(mb4 + mm) * 64 + n0];
      sm[mm][0] = bfu2f(sv.x); sm[mm][1] = bfu2f(sv.y);
      sm[mm][2] = bfu2f(sv.z); sm[mm][3] = bfu2f(sv.w);
    }
    #pragma unroll
    for (int a = 0; a < 4; ++a) {
      ushort4 qa = *(const ushort4*)&ql_s[(tr + a) * QLD + mb4];
      float q0 = bfu2f(qa.x), q1 = bfu2f(qa.y), q2 = bfu2f(qa.z), q3 = bfu2f(qa.w);
      #pragma unroll
      for (int b2 = 0; b2 < 4; ++b2)
        acc[a][b2] += q0 * sm[0][b2] + q1 * sm[1][b2] + q2 * sm[2][b2] + q3 * sm[3][b2];
    }
  }
  #pragma unroll
  for (int a = 0; a < 4; ++a) {
    float e = eL_s[tr + a];
    #pragma unroll
    for (int b2 = 0; b2 < 4; ++b2) acc[a][b2] *= e;
  }
  // intra-chunk scores P[jr][t] = coef(t,j) * (ql_t . k_jr)
  {
    int jr = tid >> 1, j = jr >> 1, tb = (tid & 1) * 32;
    float dot[32];
    #pragma unroll
    for (int t2 = 0; t2 < 32; ++t2) dot[t2] = 0.f;
    for (int m = 0; m < 64; m += 4) {
      ushort4 kb = *(const ushort4*)&kv_s[jr * 64 + m];
      float k0 = bfu2f(kb.x), k1 = bfu2f(kb.y), k2 = bfu2f(kb.z), k3 = bfu2f(kb.w);
      #pragma unroll
      for (int t2 = 0; t2 < 32; ++t2) {
        ushort4 qa = *(const ushort4*)&ql_s[(tb + t2) * QLD + m];
        dot[t2] += bfu2f(qa.x) * k0 + bfu2f(qa.y) * k1 + bfu2f(qa.z) * k2 + bfu2f(qa.w) * k3;
      }
    }
    #pragma unroll
    for (int t2 = 0; t2 < 32; ++t2) {
      int t = tb + t2;
      float coef = (j <= t) ? ud_s[j] * __expf(Lam_s[t] - Lam_s[j]) : 0.f;
      P_s[jr * 64 + t] = f2bf(dot[t2] * coef);
    }
  }
  __syncthreads();
  for (int i = tid; i < 128 * 64; i += 256) {    // reload V over K
    int jr = i >> 6, m = i & 63, j = jr >> 1, r = jr & 1;
    kv_s[i] = f2bf(proj[(size_t)(t0 + j) * 512 + 129 + r * 64 + m]);
  }
  __syncthreads();
  for (int jr = 0; jr < 128; ++jr) {
    ushort4 pu = *(const ushort4*)&P_s[jr * 64 + tr];
    ushort4 vu = *(const ushort4*)&kv_s[jr * 64 + n0];
    float p0 = bfu2f(pu.x), p1 = bfu2f(pu.y), p2 = bfu2f(pu.z), p3 = bfu2f(pu.w);
    float v0 = bfu2f(vu.x), v1 = bfu2f(vu.y), v2 = bfu2f(vu.z), v3 = bfu2f(vu.w);
    acc[0][0] += p0 * v0; acc[0][1] += p0 * v1; acc[0][2] += p0 * v2; acc[0][3] += p0 * v3;
    acc[1][0] += p1 * v0; acc[1][1] += p1 * v1; acc[1][2] += p1 * v2; acc[1][3] += p1 * v3;
    acc[2][0] += p2 * v0; acc[2][1] += p2 * v1; acc[2][2] += p2 * v2; acc[2][3] += p2 * v3;
    acc[3][0] += p3 * v0; acc[3][1] += p3 * v1; acc[3][2] += p3 * v2; acc[3][3] += p3 * v3;
  }
  // qr gate + silu + store
  #pragma unroll
  for (int a = 0; a < 4; ++a) {
    int t = t0 + tr + a;
    const float* qrp = proj + (size_t)t * 512 + 321;
    #pragma unroll
    for (int b2 = 0; b2 < 4; ++b2) {
      float rv = acc[a][b2] * qrp[n0 + b2];
      float sv = rv / (1.f + __expf(-rv));
      Rd[(size_t)t * 64 + n0 + b2] = f2bf(sv);
    }
  }
}

// ======================= launch =======================

extern "C" void kernel_launch(void* const* d_in, const int* in_sizes, int n_in,
                              void* d_out, int out_size, void* d_ws, size_t ws_size,
                              hipStream_t stream) {
  const float* x      = (const float*)d_in[0];
  const float* W_dec  = (const float*)d_in[1];
  const float* W_key  = (const float*)d_in[2];
  const float* W_val  = (const float*)d_in[3];
  const float* W_ql   = (const float*)d_in[4];
  const float* W_qr   = (const float*)d_in[5];
  const float* W_rec  = (const float*)d_in[6];
  const float* W_up   = (const float*)d_in[7];
  const float* W_gate = (const float*)d_in[8];
  const float* W_down = (const float*)d_in[9];
  const float* init_state = (const float*)d_in[10];
  float* out = (float*)d_out;

  char* w = (char*)d_ws;
  auto take = [&](size_t bytes) { char* p = w; w += (bytes + 255) & ~(size_t)255; return p; };
  __hip_bfloat16* x_bf   = (__hip_bfloat16*)take((size_t)BS * Hd * 2);
  __hip_bfloat16* Wcat_t = (__hip_bfloat16*)take((size_t)512 * Hd * 2);
  __hip_bfloat16* Wug_t  = (__hip_bfloat16*)take((size_t)4096 * Hd * 2);
  __hip_bfloat16* Wdn_t  = (__hip_bfloat16*)take((size_t)Hd * LSd * 2);
  __hip_bfloat16* Wrc_t  = (__hip_bfloat16*)take((size_t)Hd * Md * 2);
  float* proj  = (float*)take((size_t)BS * 512 * 4);
  float* Lam   = (float*)take((size_t)BS * 4);
  float* udv   = (float*)take((size_t)BS * 4);
  float* alpha = (float*)take((size_t)128 * 4);
  float* dS    = (float*)take((size_t)128 * 4096 * 4);
  float* Sin   = (float*)take((size_t)128 * 4096 * 4);
  __hip_bfloat16* Rd   = (__hip_bfloat16*)take((size_t)BS * Md * 2);
  __hip_bfloat16* hbuf = (__hip_bfloat16*)take((size_t)BS * LSd * 2);

  conv_bf16_kernel<<<8192, 256, 0, stream>>>(x, x_bf, BS * Hd);
  prep_wcat_kernel<<<2048, 256, 0, stream>>>(W_dec, W_key, W_val, W_ql, W_qr, Wcat_t);
  transpose_conv_kernel<<<dim3(64, 32), 256, 0, stream>>>(W_up,   Wug_t, Hd, LSd, 0);
  transpose_conv_kernel<<<dim3(64, 32), 256, 0, stream>>>(W_gate, Wug_t, Hd, LSd, 2048);
  transpose_conv_kernel<<<dim3(32, 64), 256, 0, stream>>>(W_down, Wdn_t, LSd, Hd, 0);
  transpose_conv_kernel<<<dim3(32, 2),  256, 0, stream>>>(W_rec,  Wrc_t, Md, Hd, 0);

  gemm_proj_kernel<<<dim3(4, 64), 256, 0, stream>>>(x_bf, Wcat_t, proj);

  scan_chunk_kernel<<<128, 256, 0, stream>>>(proj, Lam, udv, alpha, dS);
  scan_cross_kernel<<<64, 256, 0, stream>>>(dS, alpha, init_state, Sin);
  scan_read_kernel<<<128, 256, 0, stream>>>(proj, Lam, udv, Sin, Rd);

  gemm_upgate_kernel<<<dim3(16, 64), 256, 0, stream>>>(x_bf, Wug_t, hbuf);
  gemm_final_kernel<<<dim3(8, 64), 256, 0, stream>>>(hbuf, Wdn_t, Rd, Wrc_t, out);
}

// Round 3
// 318.825 us; speedup vs baseline: 1.1889x; 1.1889x over previous
//
#include <hip/hip_runtime.h>
#include <hip/hip_bf16.h>

typedef __bf16 bf16x8 __attribute__((ext_vector_type(8)));
typedef float f32x4 __attribute__((ext_vector_type(4)));

#define BS   8192   // B*S rows
#define Hd   1024
#define LSd  2048
#define Md   64

static __device__ __forceinline__ float bfu2f(unsigned short u) {
  return __uint_as_float(((unsigned int)u) << 16);
}
static __device__ __forceinline__ __hip_bfloat16 f2bf(float f) { return __float2bfloat16(f); }

// ===================== fragment-major tiled layout =====================
// Matrix X[RowDim][K] (operand form: both A and "B^T" are [dim128][K]) stored as
// 8KB tiles of 128 rows x 32 k. Within tile: chunk ri=(row>>4)&7 (512 elems),
// lane slot l=(row&15)+16*((k>>3)&3), elem e=k&7.
// flat = tile*4096 + ri*512 + l*8 + e,  tile = (row>>7)*(K>>5) + (k>>5).
// GEMM stages chunk ri with ONE global_load_lds: lane l reads 16B at
// tile_base + ri*512 + l*8 (contiguous 1KB) -> LDS dst + ri*512 + lane*16B
// (contiguous). MFMA fragment read = base + lane*16B (conflict-free, measured 0).

// ======================= prep kernels =======================

// x f32 [8192][1024] -> frag tiles. One wave per chunk (16 rows x 32 k).
__global__ __launch_bounds__(256) void conv_frag_kernel(const float* __restrict__ src,
    __hip_bfloat16* __restrict__ dst) {
  int wid = (blockIdx.x * 256 + threadIdx.x) >> 6;   // chunk id, 16384 total
  int lane = threadIdx.x & 63;
  int t = wid >> 3, ri = wid & 7;
  int mb = t >> 5, kt = t & 31;
  int row = mb * 128 + ri * 16 + (lane & 15);
  int k = kt * 32 + (lane >> 4) * 8;
  const float* s = src + (size_t)row * 1024 + k;
  float4 f0 = *(const float4*)s;
  float4 f1 = *(const float4*)(s + 4);
  union { unsigned short u8[8]; uint4 v; } o;
  o.u8[0] = __bfloat16_as_ushort(f2bf(f0.x)); o.u8[1] = __bfloat16_as_ushort(f2bf(f0.y));
  o.u8[2] = __bfloat16_as_ushort(f2bf(f0.z)); o.u8[3] = __bfloat16_as_ushort(f2bf(f0.w));
  o.u8[4] = __bfloat16_as_ushort(f2bf(f1.x)); o.u8[5] = __bfloat16_as_ushort(f2bf(f1.y));
  o.u8[6] = __bfloat16_as_ushort(f2bf(f1.z)); o.u8[7] = __bfloat16_as_ushort(f2bf(f1.w));
  *(uint4*)(dst + (size_t)wid * 512 + lane * 8) = o.v;
}

// Wcat frag: N=512 (n=0 decay,1..128 key,129..256 value,257..320 ql,321..384 qr), K=1024
__global__ __launch_bounds__(256) void prep_wcat_frag_kernel(const float* __restrict__ Wd,
    const float* __restrict__ Wk, const float* __restrict__ Wv,
    const float* __restrict__ Wql, const float* __restrict__ Wqr,
    __hip_bfloat16* __restrict__ out) {
  int i = blockIdx.x * 256 + threadIdx.x;   // 512*1024 total
  int t = i >> 12, ri = (i >> 9) & 7, l = (i >> 3) & 63, e = i & 7;
  int n = (t >> 5) * 128 + ri * 16 + (l & 15);
  int h = (t & 31) * 32 + (l >> 4) * 8 + e;
  float v = 0.f;
  if (n == 0)        v = Wd[h];
  else if (n < 129)  v = Wk[h * 128 + (n - 1)];
  else if (n < 257)  v = Wv[h * 128 + (n - 129)];
  else if (n < 321)  v = Wql[h * 64 + (n - 257)];
  else if (n < 385)  v = Wqr[h * 64 + (n - 321)];
  out[i] = f2bf(v);
}

// src f32 [Ktot][Nsrc] row-major -> frag tiles of B^T[n][k]; one block per (kt, nb)
__global__ __launch_bounds__(256) void transpose_frag_kernel(const float* __restrict__ src,
    __hip_bfloat16* __restrict__ dst, int Ktot, int Nsrc, int n_off) {
  __shared__ float tile[32][129];
  int kt = blockIdx.x, nb = blockIdx.y;
  int k0 = kt * 32, n0 = nb * 128;
  int tid = threadIdx.x;
  int kr = tid >> 3, nc = (tid & 7) * 16;
  const float* s = src + (size_t)(k0 + kr) * Nsrc + n0 + nc;
  #pragma unroll
  for (int u = 0; u < 16; u += 4) {
    float4 f = *(const float4*)(s + u);
    tile[kr][nc + u + 0] = f.x; tile[kr][nc + u + 1] = f.y;
    tile[kr][nc + u + 2] = f.z; tile[kr][nc + u + 3] = f.w;
  }
  __syncthreads();
  int wave = tid >> 6, lane = tid & 63;
  int tIdx = ((n0 + n_off) >> 7) * (Ktot >> 5) + kt;
  __hip_bfloat16* d = dst + ((size_t)tIdx << 12);
  #pragma unroll
  for (int it = 0; it < 2; ++it) {
    int ri = wave * 2 + it;
    int nl = ri * 16 + (lane & 15), kq = (lane >> 4) * 8;
    union { unsigned short u8[8]; uint4 v; } o;
    #pragma unroll
    for (int e = 0; e < 8; ++e)
      o.u8[e] = __bfloat16_as_ushort(f2bf(tile[kq + e][nl]));
    *(uint4*)(d + ri * 512 + lane * 8) = o.v;
  }
}

// ======================= GEMM core =======================

static __device__ __forceinline__ void stage_async_frag(const __hip_bfloat16* __restrict__ tile_src,
    __hip_bfloat16* __restrict__ dst, int wave, int lane) {
  #pragma unroll
  for (int it = 0; it < 2; ++it) {
    int ri = wave * 2 + it;
    __builtin_amdgcn_global_load_lds(
        (const __attribute__((address_space(1))) void*)(tile_src + ri * 512 + lane * 8),
        (__attribute__((address_space(3))) void*)(dst + ri * 512),
        16, 0, 0);
  }
}

static __device__ __forceinline__ void mfma_single(const __hip_bfloat16* sA, const __hip_bfloat16* sB,
    int wm16, int wn16, int lane, f32x4 acc[4][4]) {
  bf16x8 af[4], bg[4];
  #pragma unroll
  for (int i = 0; i < 4; ++i) af[i] = *(const bf16x8*)(sA + (wm16 + i) * 512 + lane * 8);
  #pragma unroll
  for (int j = 0; j < 4; ++j) bg[j] = *(const bf16x8*)(sB + (wn16 + j) * 512 + lane * 8);
  #pragma unroll
  for (int i = 0; i < 4; ++i)
    #pragma unroll
    for (int j = 0; j < 4; ++j)
      acc[i][j] = __builtin_amdgcn_mfma_f32_16x16x32_bf16(af[i], bg[j], acc[i][j], 0, 0, 0);
}

static __device__ __forceinline__ void mfma_dual(const __hip_bfloat16* sA,
    const __hip_bfloat16* sBu, const __hip_bfloat16* sBg,
    int wm16, int wn16, int lane, f32x4 accu[4][4], f32x4 accg[4][4]) {
  bf16x8 af[4], bu[4], bg[4];
  #pragma unroll
  for (int i = 0; i < 4; ++i) af[i] = *(const bf16x8*)(sA + (wm16 + i) * 512 + lane * 8);
  #pragma unroll
  for (int j = 0; j < 4; ++j) bu[j] = *(const bf16x8*)(sBu + (wn16 + j) * 512 + lane * 8);
  #pragma unroll
  for (int j = 0; j < 4; ++j) bg[j] = *(const bf16x8*)(sBg + (wn16 + j) * 512 + lane * 8);
  #pragma unroll
  for (int i = 0; i < 4; ++i)
    #pragma unroll
    for (int j = 0; j < 4; ++j) {
      accu[i][j] = __builtin_amdgcn_mfma_f32_16x16x32_bf16(af[i], bu[j], accu[i][j], 0, 0, 0);
      accg[i][j] = __builtin_amdgcn_mfma_f32_16x16x32_bf16(af[i], bg[j], accg[i][j], 0, 0, 0);
    }
}

// proj = x @ Wcat^T : C[8192][512] f32.  A frag K=1024 (32 ktiles), B frag K=1024
__global__ __launch_bounds__(256, 2) void gemm_proj_kernel(const __hip_bfloat16* __restrict__ A,
    const __hip_bfloat16* __restrict__ Bt, float* __restrict__ C) {
  __shared__ __align__(16) __hip_bfloat16 sA[4096];
  __shared__ __align__(16) __hip_bfloat16 sB[4096];
  int tid = threadIdx.x, nb = blockIdx.x, mb = blockIdx.y;
  int wave = tid >> 6, lane = tid & 63;
  int wm16 = (wave >> 1) * 4, wn16 = (wave & 1) * 4;
  int fr = lane & 15, q4 = (lane >> 4) * 4;
  f32x4 acc[4][4] = {};
  for (int kt = 0; kt < 32; ++kt) {
    __syncthreads();
    stage_async_frag(A + ((size_t)(mb * 32 + kt) << 12), sA, wave, lane);
    stage_async_frag(Bt + ((size_t)(nb * 32 + kt) << 12), sB, wave, lane);
    __syncthreads();
    mfma_single(sA, sB, wm16, wn16, lane, acc);
  }
  #pragma unroll
  for (int i = 0; i < 4; ++i)
    #pragma unroll
    for (int j = 0; j < 4; ++j) {
      int row = mb * 128 + (wm16 + i) * 16 + q4;
      int col = nb * 128 + (wn16 + j) * 16 + fr;
      #pragma unroll
      for (int rg = 0; rg < 4; ++rg)
        C[(size_t)(row + rg) * 512 + col] = acc[i][j][rg];
    }
}

// h = (x@W_up) * silu(x@W_gate); hbuf written in frag layout (K=LSd for final GEMM)
__global__ __launch_bounds__(256, 2) void gemm_upgate_kernel(const __hip_bfloat16* __restrict__ A,
    const __hip_bfloat16* __restrict__ Bt, __hip_bfloat16* __restrict__ hout) {
  __shared__ __align__(16) __hip_bfloat16 sA[4096];
  __shared__ __align__(16) __hip_bfloat16 sBu[4096];
  __shared__ __align__(16) __hip_bfloat16 sBg[4096];
  int tid = threadIdx.x, nb = blockIdx.x, mb = blockIdx.y;
  int wave = tid >> 6, lane = tid & 63;
  int wm16 = (wave >> 1) * 4, wn16 = (wave & 1) * 4;
  int fr = lane & 15, q4 = (lane >> 4) * 4;
  f32x4 accu[4][4] = {}, accg[4][4] = {};
  for (int kt = 0; kt < 32; ++kt) {
    __syncthreads();
    stage_async_frag(A + ((size_t)(mb * 32 + kt) << 12), sA, wave, lane);
    stage_async_frag(Bt + ((size_t)(nb * 32 + kt) << 12), sBu, wave, lane);
    stage_async_frag(Bt + ((size_t)((nb + 16) * 32 + kt) << 12), sBg, wave, lane);
    __syncthreads();
    mfma_dual(sA, sBu, sBg, wm16, wn16, lane, accu, accg);
  }
  #pragma unroll
  for (int i = 0; i < 4; ++i)
    #pragma unroll
    for (int j = 0; j < 4; ++j) {
      int col = nb * 128 + (wn16 + j) * 16 + fr;
      int q = (col >> 3) & 3, e = col & 7;
      size_t base = ((size_t)(mb * 64 + (col >> 5)) << 12) + (wm16 + i) * 512 + q * 128 + e;
      #pragma unroll
      for (int rg = 0; rg < 4; ++rg) {
        float u = accu[i][j][rg], g = accg[i][j][rg];
        float hv = u * g / (1.f + __expf(-g));
        hout[base + (q4 + rg) * 8] = f2bf(hv);
      }
    }
}

// out = h@Wdown^T + Rd@Wrec^T  (frag K=2048 then K=64), f32 out
__global__ __launch_bounds__(256, 2) void gemm_final_kernel(const __hip_bfloat16* __restrict__ A,
    const __hip_bfloat16* __restrict__ Bt, const __hip_bfloat16* __restrict__ A2,
    const __hip_bfloat16* __restrict__ B2t, float* __restrict__ C) {
  __shared__ __align__(16) __hip_bfloat16 sA[4096];
  __shared__ __align__(16) __hip_bfloat16 sB[4096];
  int tid = threadIdx.x, nb = blockIdx.x, mb = blockIdx.y;
  int wave = tid >> 6, lane = tid & 63;
  int wm16 = (wave >> 1) * 4, wn16 = (wave & 1) * 4;
  int fr = lane & 15, q4 = (lane >> 4) * 4;
  f32x4 acc[4][4] = {};
  for (int kt = 0; kt < 64; ++kt) {
    __syncthreads();
    stage_async_frag(A + ((size_t)(mb * 64 + kt) << 12), sA, wave, lane);
    stage_async_frag(Bt + ((size_t)(nb * 64 + kt) << 12), sB, wave, lane);
    __syncthreads();
    mfma_single(sA, sB, wm16, wn16, lane, acc);
  }
  #pragma unroll
  for (int kt = 0; kt < 2; ++kt) {
    __syncthreads();
    stage_async_frag(A2 + ((size_t)(mb * 2 + kt) << 12), sA, wave, lane);
    stage_async_frag(B2t + ((size_t)(nb * 2 + kt) << 12), sB, wave, lane);
    __syncthreads();
    mfma_single(sA, sB, wm16, wn16, lane, acc);
  }
  #pragma unroll
  for (int i = 0; i < 4; ++i)
    #pragma unroll
    for (int j = 0; j < 4; ++j) {
      int row = mb * 128 + (wm16 + i) * 16 + q4;
      int col = nb * 128 + (wn16 + j) * 16 + fr;
      #pragma unroll
      for (int rg = 0; rg < 4; ++rg)
        C[(size_t)(row + rg) * Hd + col] = acc[i][j][rg];
    }
}

// ======================= recurrent (chunked gated linear attention) =======================
// chunk C=64. proj row layout: [0]=z_decay, [1..129)=key(r*64+m), [129..257)=value, [257..321)=ql, [321..385)=qr

__global__ __launch_bounds__(256) void scan_chunk_kernel(const float* __restrict__ proj,
    float* __restrict__ Lam, float* __restrict__ udv, float* __restrict__ alpha,
    float* __restrict__ dS) {
  int bc = blockIdx.x, t0 = bc * 64, tid = threadIdx.x;
  __shared__ float d_s[64], ld_s[64], Lam_s[64], u_s[64];
  __shared__ __align__(16) __hip_bfloat16 k_s[128 * 64];
  __shared__ __align__(16) __hip_bfloat16 v_s[128 * 64];
  if (tid < 64) {
    float z = proj[(size_t)(t0 + tid) * 512];
    float dd = 1.f / (1.f + __expf(-z));
    float l = (z >= 0.f) ? -log1pf(__expf(-z)) : (z - log1pf(__expf(z)));
    d_s[tid] = dd; ld_s[tid] = l;
  }
  __syncthreads();
  if (tid == 0) {
    float s = 0.f;
    for (int j = 0; j < 64; ++j) { s += ld_s[j]; Lam_s[j] = s; }
  }
  __syncthreads();
  float Lend = Lam_s[63];
  if (tid < 64) {
    u_s[tid] = (1.f - d_s[tid]) * __expf(Lend - Lam_s[tid]) * 0.5f;  // includes 1/R
    Lam[t0 + tid] = Lam_s[tid];
    udv[t0 + tid] = (1.f - d_s[tid]) * 0.5f;                          // includes 1/R
  }
  if (tid == 0) alpha[bc] = __expf(Lend);
  __syncthreads();
  for (int i = tid; i < 128 * 64; i += 256) {
    int jr = i >> 6, m = i & 63, j = jr >> 1, r = jr & 1;
    const float* rowp = proj + (size_t)(t0 + j) * 512;
    k_s[i] = f2bf(u_s[j] * rowp[1 + r * 64 + m]);
    v_s[i] = f2bf(rowp[129 + r * 64 + m]);
  }
  __syncthreads();
  int m0 = (tid & 15) * 4, n0 = (tid >> 4) * 4;
  float acc[4][4] = {{0.f}};
  for (int jr = 0; jr < 128; ++jr) {
    ushort4 ku = *(const ushort4*)&k_s[jr * 64 + m0];
    ushort4 vu = *(const ushort4*)&v_s[jr * 64 + n0];
    float k0 = bfu2f(ku.x), k1 = bfu2f(ku.y), k2 = bfu2f(ku.z), k3 = bfu2f(ku.w);
    float v0 = bfu2f(vu.x), v1 = bfu2f(vu.y), v2 = bfu2f(vu.z), v3 = bfu2f(vu.w);
    acc[0][0] += k0 * v0; acc[0][1] += k0 * v1; acc[0][2] += k0 * v2; acc[0][3] += k0 * v3;
    acc[1][0] += k1 * v0; acc[1][1] += k1 * v1; acc[1][2] += k1 * v2; acc[1][3] += k1 * v3;
    acc[2][0] += k2 * v0; acc[2][1] += k2 * v1; acc[2][2] += k2 * v2; acc[2][3] += k2 * v3;
    acc[3][0] += k3 * v0; acc[3][1] += k3 * v1; acc[3][2] += k3 * v2; acc[3][3] += k3 * v3;
  }
  float* outp = dS + (size_t)bc * 4096;
  #pragma unroll
  for (int a = 0; a < 4; ++a)
    #pragma unroll
    for (int b2 = 0; b2 < 4; ++b2)
      outp[(m0 + a) * 64 + (n0 + b2)] = acc[a][b2];
}

__global__ __launch_bounds__(256) void scan_cross_kernel(const float* __restrict__ dS,
    const float* __restrict__ alpha, const float* __restrict__ init_state,
    float* __restrict__ Sin) {
  int idx = blockIdx.x * 256 + threadIdx.x;   // 4 batches * 4096 elems
  int b = idx >> 12, e = idx & 4095;
  float s = init_state[e];
  for (int c = 0; c < 32; ++c) {
    int bc = b * 32 + c;
    Sin[(size_t)bc * 4096 + e] = s;
    s = alpha[bc] * s + dS[(size_t)bc * 4096 + e];
  }
}

#define QLD 68

__global__ __launch_bounds__(256) void scan_read_kernel(const float* __restrict__ proj,
    const float* __restrict__ Lam, const float* __restrict__ udv,
    const float* __restrict__ Sin, __hip_bfloat16* __restrict__ Rd) {
  int bc = blockIdx.x, t0 = bc * 64, tid = threadIdx.x;
  __shared__ __align__(16) __hip_bfloat16 ql_s[64 * QLD];
  __shared__ __align__(16) __hip_bfloat16 kv_s[128 * 64];   // K then V
  __shared__ __align__(16) __hip_bfloat16 S_s[64 * 64];
  __shared__ __align__(16) __hip_bfloat16 P_s[128 * 64];    // [jr][t]
  __shared__ float Lam_s[64], ud_s[64], eL_s[64];
  for (int i = tid; i < 64 * 64; i += 256) {
    int t = i >> 6, m = i & 63;
    ql_s[t * QLD + m] = f2bf(proj[(size_t)(t0 + t) * 512 + 257 + m]);
    S_s[i] = f2bf(Sin[(size_t)bc * 4096 + i]);
  }
  for (int i = tid; i < 128 * 64; i += 256) {
    int jr = i >> 6, m = i & 63, j = jr >> 1, r = jr & 1;
    kv_s[i] = f2bf(proj[(size_t)(t0 + j) * 512 + 1 + r * 64 + m]);
  }
  if (tid < 64) {
    float L = Lam[t0 + tid];
    Lam_s[tid] = L; ud_s[tid] = udv[t0 + tid]; eL_s[tid] = __expf(L);
  }
  __syncthreads();
  int tr = (tid & 15) * 4, n0 = (tid >> 4) * 4;
  float acc[4][4] = {{0.f}};
  for (int mb4 = 0; mb4 < 64; mb4 += 4) {
    float sm[4][4];
    #pragma unroll
    for (int mm = 0; mm < 4; ++mm) {
      ushort4 sv = *(const ushort4*)&S_s[(mb4 + mm) * 64 + n0];
      sm[mm][0] = bfu2f(sv.x); sm[mm][1] = bfu2f(sv.y);
      sm[mm][2] = bfu2f(sv.z); sm[mm][3] = bfu2f(sv.w);
    }
    #pragma unroll
    for (int a = 0; a < 4; ++a) {
      ushort4 qa = *(const ushort4*)&ql_s[(tr + a) * QLD + mb4];
      float q0 = bfu2f(qa.x), q1 = bfu2f(qa.y), q2 = bfu2f(qa.z), q3 = bfu2f(qa.w);
      #pragma unroll
      for (int b2 = 0; b2 < 4; ++b2)
        acc[a][b2] += q0 * sm[0][b2] + q1 * sm[1][b2] + q2 * sm[2][b2] + q3 * sm[3][b2];
    }
  }
  #pragma unroll
  for (int a = 0; a < 4; ++a) {
    float e = eL_s[tr + a];
    #pragma unroll
    for (int b2 = 0; b2 < 4; ++b2) acc[a][b2] *= e;
  }
  {
    int jr = tid >> 1, j = jr >> 1, tb = (tid & 1) * 32;
    float dot[32];
    #pragma unroll
    for (int t2 = 0; t2 < 32; ++t2) dot[t2] = 0.f;
    for (int m = 0; m < 64; m += 4) {
      ushort4 kb = *(const ushort4*)&kv_s[jr * 64 + m];
      float k0 = bfu2f(kb.x), k1 = bfu2f(kb.y), k2 = bfu2f(kb.z), k3 = bfu2f(kb.w);
      #pragma unroll
      for (int t2 = 0; t2 < 32; ++t2) {
        ushort4 qa = *(const ushort4*)&ql_s[(tb + t2) * QLD + m];
        dot[t2] += bfu2f(qa.x) * k0 + bfu2f(qa.y) * k1 + bfu2f(qa.z) * k2 + bfu2f(qa.w) * k3;
      }
    }
    #pragma unroll
    for (int t2 = 0; t2 < 32; ++t2) {
      int t = tb + t2;
      float coef = (j <= t) ? ud_s[j] * __expf(Lam_s[t] - Lam_s[j]) : 0.f;
      P_s[jr * 64 + t] = f2bf(dot[t2] * coef);
    }
  }
  __syncthreads();
  for (int i = tid; i < 128 * 64; i += 256) {    // reload V over K
    int jr = i >> 6, m = i & 63, j = jr >> 1, r = jr & 1;
    kv_s[i] = f2bf(proj[(size_t)(t0 + j) * 512 + 129 + r * 64 + m]);
  }
  __syncthreads();
  for (int jr = 0; jr < 128; ++jr) {
    ushort4 pu = *(const ushort4*)&P_s[jr * 64 + tr];
    ushort4 vu = *(const ushort4*)&kv_s[jr * 64 + n0];
    float p0 = bfu2f(pu.x), p1 = bfu2f(pu.y), p2 = bfu2f(pu.z), p3 = bfu2f(pu.w);
    float v0 = bfu2f(vu.x), v1 = bfu2f(vu.y), v2 = bfu2f(vu.z), v3 = bfu2f(vu.w);
    acc[0][0] += p0 * v0; acc[0][1] += p0 * v1; acc[0][2] += p0 * v2; acc[0][3] += p0 * v3;
    acc[1][0] += p1 * v0; acc[1][1] += p1 * v1; acc[1][2] += p1 * v2; acc[1][3] += p1 * v3;
    acc[2][0] += p2 * v0; acc[2][1] += p2 * v1; acc[2][2] += p2 * v2; acc[2][3] += p2 * v3;
    acc[3][0] += p3 * v0; acc[3][1] += p3 * v1; acc[3][2] += p3 * v2; acc[3][3] += p3 * v3;
  }
  // qr gate + silu + store Rd in FRAG layout (RowDim=8192, K=64 -> 2 ktiles)
  #pragma unroll
  for (int a = 0; a < 4; ++a) {
    int row = t0 + tr + a;
    const float* qrp = proj + (size_t)row * 512 + 321;
    int tBase = (row >> 7) * 2, ri = (row >> 4) & 7, rl = row & 15;
    #pragma unroll
    for (int b2 = 0; b2 < 4; ++b2) {
      int n = n0 + b2;
      float rv = acc[a][b2] * qrp[n];
      float sv = rv / (1.f + __expf(-rv));
      size_t idx = ((size_t)(tBase + (n >> 5)) << 12) + ri * 512
                 + (rl + ((n >> 3) & 3) * 16) * 8 + (n & 7);
      Rd[idx] = f2bf(sv);
    }
  }
}

// ======================= launch =======================

extern "C" void kernel_launch(void* const* d_in, const int* in_sizes, int n_in,
                              void* d_out, int out_size, void* d_ws, size_t ws_size,
                              hipStream_t stream) {
  const float* x      = (const float*)d_in[0];
  const float* W_dec  = (const float*)d_in[1];
  const float* W_key  = (const float*)d_in[2];
  const float* W_val  = (const float*)d_in[3];
  const float* W_ql   = (const float*)d_in[4];
  const float* W_qr   = (const float*)d_in[5];
  const float* W_rec  = (const float*)d_in[6];
  const float* W_up   = (const float*)d_in[7];
  const float* W_gate = (const float*)d_in[8];
  const float* W_down = (const float*)d_in[9];
  const float* init_state = (const float*)d_in[10];
  float* out = (float*)d_out;

  char* w = (char*)d_ws;
  auto take = [&](size_t bytes) { char* p = w; w += (bytes + 255) & ~(size_t)255; return p; };
  __hip_bfloat16* x_fb   = (__hip_bfloat16*)take((size_t)BS * Hd * 2);
  __hip_bfloat16* Wcat_f = (__hip_bfloat16*)take((size_t)512 * Hd * 2);
  __hip_bfloat16* Wug_f  = (__hip_bfloat16*)take((size_t)4096 * Hd * 2);
  __hip_bfloat16* Wdn_f  = (__hip_bfloat16*)take((size_t)Hd * LSd * 2);
  __hip_bfloat16* Wrc_f  = (__hip_bfloat16*)take((size_t)Hd * Md * 2);
  float* proj  = (float*)take((size_t)BS * 512 * 4);
  float* Lam   = (float*)take((size_t)BS * 4);
  float* udv   = (float*)take((size_t)BS * 4);
  float* alpha = (float*)take((size_t)128 * 4);
  float* dS    = (float*)take((size_t)128 * 4096 * 4);
  float* Sin   = (float*)take((size_t)128 * 4096 * 4);
  __hip_bfloat16* Rd   = (__hip_bfloat16*)take((size_t)BS * Md * 2);
  __hip_bfloat16* hbuf = (__hip_bfloat16*)take((size_t)BS * LSd * 2);

  conv_frag_kernel<<<4096, 256, 0, stream>>>(x, x_fb);
  prep_wcat_frag_kernel<<<2048, 256, 0, stream>>>(W_dec, W_key, W_val, W_ql, W_qr, Wcat_f);
  transpose_frag_kernel<<<dim3(32, 16), 256, 0, stream>>>(W_up,   Wug_f, Hd, LSd, 0);
  transpose_frag_kernel<<<dim3(32, 16), 256, 0, stream>>>(W_gate, Wug_f, Hd, LSd, 2048);
  transpose_frag_kernel<<<dim3(64, 8),  256, 0, stream>>>(W_down, Wdn_f, LSd, Hd, 0);
  transpose_frag_kernel<<<dim3(2, 8),   256, 0, stream>>>(W_rec,  Wrc_f, Md, Hd, 0);

  gemm_proj_kernel<<<dim3(4, 64), 256, 0, stream>>>(x_fb, Wcat_f, proj);

  scan_chunk_kernel<<<128, 256, 0, stream>>>(proj, Lam, udv, alpha, dS);
  scan_cross_kernel<<<64, 256, 0, stream>>>(dS, alpha, init_state, Sin);
  scan_read_kernel<<<128, 256, 0, stream>>>(proj, Lam, udv, Sin, Rd);

  gemm_upgate_kernel<<<dim3(16, 64), 256, 0, stream>>>(x_fb, Wug_f, hbuf);
  gemm_final_kernel<<<dim3(8, 64), 256, 0, stream>>>(hbuf, Wdn_f, Rd, Wrc_f, out);
}

// Round 4
// 301.659 us; speedup vs baseline: 1.2566x; 1.0569x over previous
//
#include <hip/hip_runtime.h>
#include <hip/hip_bf16.h>

typedef __bf16 bf16x8 __attribute__((ext_vector_type(8)));
typedef float f32x4 __attribute__((ext_vector_type(4)));

#define BS   8192   // B*S rows
#define Hd   1024
#define LSd  2048
#define Md   64

static __device__ __forceinline__ float bfu2f(unsigned short u) {
  return __uint_as_float(((unsigned int)u) << 16);
}
static __device__ __forceinline__ __hip_bfloat16 f2bf(float f) { return __float2bfloat16(f); }

// ===================== fragment-major tiled layout =====================
// Matrix X[RowDim][K] (operand form: both A and "B^T" are [dim128][K]) stored as
// 8KB tiles of 128 rows x 32 k. Within tile: chunk ri=(row>>4)&7 (512 elems),
// lane slot l=(row&15)+16*((k>>3)&3), elem e=k&7.
// flat = tile*4096 + ri*512 + l*8 + e,  tile = (row>>7)*(K>>5) + (k>>5).
// GEMM stages chunk ri with ONE global_load_lds: lane l reads 16B at
// tile_base + ri*512 + l*8 (contiguous 1KB) -> LDS dst + ri*512 + lane*16B
// (contiguous). MFMA fragment read = base + lane*16B (conflict-free, measured 0).

// ======================= prep kernels =======================

// x f32 [8192][1024] -> frag tiles. One wave per chunk (16 rows x 32 k).
__global__ __launch_bounds__(256) void conv_frag_kernel(const float* __restrict__ src,
    __hip_bfloat16* __restrict__ dst) {
  int wid = (blockIdx.x * 256 + threadIdx.x) >> 6;   // chunk id, 16384 total
  int lane = threadIdx.x & 63;
  int t = wid >> 3, ri = wid & 7;
  int mb = t >> 5, kt = t & 31;
  int row = mb * 128 + ri * 16 + (lane & 15);
  int k = kt * 32 + (lane >> 4) * 8;
  const float* s = src + (size_t)row * 1024 + k;
  float4 f0 = *(const float4*)s;
  float4 f1 = *(const float4*)(s + 4);
  union { unsigned short u8[8]; uint4 v; } o;
  o.u8[0] = __bfloat16_as_ushort(f2bf(f0.x)); o.u8[1] = __bfloat16_as_ushort(f2bf(f0.y));
  o.u8[2] = __bfloat16_as_ushort(f2bf(f0.z)); o.u8[3] = __bfloat16_as_ushort(f2bf(f0.w));
  o.u8[4] = __bfloat16_as_ushort(f2bf(f1.x)); o.u8[5] = __bfloat16_as_ushort(f2bf(f1.y));
  o.u8[6] = __bfloat16_as_ushort(f2bf(f1.z)); o.u8[7] = __bfloat16_as_ushort(f2bf(f1.w));
  *(uint4*)(dst + (size_t)wid * 512 + lane * 8) = o.v;
}

// Wcat frag: N=512 (n=0 decay,1..128 key,129..256 value,257..320 ql,321..384 qr), K=1024
__global__ __launch_bounds__(256) void prep_wcat_frag_kernel(const float* __restrict__ Wd,
    const float* __restrict__ Wk, const float* __restrict__ Wv,
    const float* __restrict__ Wql, const float* __restrict__ Wqr,
    __hip_bfloat16* __restrict__ out) {
  int i = blockIdx.x * 256 + threadIdx.x;   // 512*1024 total
  int t = i >> 12, ri = (i >> 9) & 7, l = (i >> 3) & 63, e = i & 7;
  int n = (t >> 5) * 128 + ri * 16 + (l & 15);
  int h = (t & 31) * 32 + (l >> 4) * 8 + e;
  float v = 0.f;
  if (n == 0)        v = Wd[h];
  else if (n < 129)  v = Wk[h * 128 + (n - 1)];
  else if (n < 257)  v = Wv[h * 128 + (n - 129)];
  else if (n < 321)  v = Wql[h * 64 + (n - 257)];
  else if (n < 385)  v = Wqr[h * 64 + (n - 321)];
  out[i] = f2bf(v);
}

// All 4 weight transposes in one launch: src f32 [Ktot][Nsrc] -> frag B^T[n][k]
__global__ __launch_bounds__(256) void transpose_all_kernel(
    const float* __restrict__ Wup, const float* __restrict__ Wgate,
    const float* __restrict__ Wdown, const float* __restrict__ Wrec,
    __hip_bfloat16* __restrict__ Wug_f, __hip_bfloat16* __restrict__ Wdn_f,
    __hip_bfloat16* __restrict__ Wrc_f) {
  __shared__ float tile[32][129];
  int b = blockIdx.x;
  const float* src; __hip_bfloat16* dst; int Ktot, Nsrc, n_off, kt, nb;
  if (b < 512)        { src = Wup;   dst = Wug_f; Ktot = 1024; Nsrc = 2048; n_off = 0;    int r = b;        kt = r & 31; nb = r >> 5; }
  else if (b < 1024)  { src = Wgate; dst = Wug_f; Ktot = 1024; Nsrc = 2048; n_off = 2048; int r = b - 512;  kt = r & 31; nb = r >> 5; }
  else if (b < 1536)  { src = Wdown; dst = Wdn_f; Ktot = 2048; Nsrc = 1024; n_off = 0;    int r = b - 1024; kt = r & 63; nb = r >> 6; }
  else                { src = Wrec;  dst = Wrc_f; Ktot = 64;   Nsrc = 1024; n_off = 0;    int r = b - 1536; kt = r & 1;  nb = r >> 1; }
  int k0 = kt * 32, n0 = nb * 128;
  int tid = threadIdx.x;
  int kr = tid >> 3, nc = (tid & 7) * 16;
  const float* s = src + (size_t)(k0 + kr) * Nsrc + n0 + nc;
  #pragma unroll
  for (int u = 0; u < 16; u += 4) {
    float4 f = *(const float4*)(s + u);
    tile[kr][nc + u + 0] = f.x; tile[kr][nc + u + 1] = f.y;
    tile[kr][nc + u + 2] = f.z; tile[kr][nc + u + 3] = f.w;
  }
  __syncthreads();
  int wave = tid >> 6, lane = tid & 63;
  int tIdx = ((n0 + n_off) >> 7) * (Ktot >> 5) + kt;
  __hip_bfloat16* d = dst + ((size_t)tIdx << 12);
  #pragma unroll
  for (int it = 0; it < 2; ++it) {
    int ri = wave * 2 + it;
    int nl = ri * 16 + (lane & 15), kq = (lane >> 4) * 8;
    union { unsigned short u8[8]; uint4 v; } o;
    #pragma unroll
    for (int e = 0; e < 8; ++e)
      o.u8[e] = __bfloat16_as_ushort(f2bf(tile[kq + e][nl]));
    *(uint4*)(d + ri * 512 + lane * 8) = o.v;
  }
}

// ======================= GEMM core =======================

static __device__ __forceinline__ void stage_async_frag(const __hip_bfloat16* __restrict__ tile_src,
    __hip_bfloat16* __restrict__ dst, int wave, int lane) {
  #pragma unroll
  for (int it = 0; it < 2; ++it) {
    int ri = wave * 2 + it;
    __builtin_amdgcn_global_load_lds(
        (const __attribute__((address_space(1))) void*)(tile_src + ri * 512 + lane * 8),
        (__attribute__((address_space(3))) void*)(dst + ri * 512),
        16, 0, 0);
  }
}

static __device__ __forceinline__ void mfma_single(const __hip_bfloat16* sA, const __hip_bfloat16* sB,
    int wm16, int wn16, int lane, f32x4 acc[4][4]) {
  bf16x8 af[4], bg[4];
  #pragma unroll
  for (int i = 0; i < 4; ++i) af[i] = *(const bf16x8*)(sA + (wm16 + i) * 512 + lane * 8);
  #pragma unroll
  for (int j = 0; j < 4; ++j) bg[j] = *(const bf16x8*)(sB + (wn16 + j) * 512 + lane * 8);
  #pragma unroll
  for (int i = 0; i < 4; ++i)
    #pragma unroll
    for (int j = 0; j < 4; ++j)
      acc[i][j] = __builtin_amdgcn_mfma_f32_16x16x32_bf16(af[i], bg[j], acc[i][j], 0, 0, 0);
}

static __device__ __forceinline__ void mfma_dual(const __hip_bfloat16* sA,
    const __hip_bfloat16* sBu, const __hip_bfloat16* sBg,
    int wm16, int wn16, int lane, f32x4 accu[4][4], f32x4 accg[4][4]) {
  bf16x8 af[4], bu[4], bg[4];
  #pragma unroll
  for (int i = 0; i < 4; ++i) af[i] = *(const bf16x8*)(sA + (wm16 + i) * 512 + lane * 8);
  #pragma unroll
  for (int j = 0; j < 4; ++j) bu[j] = *(const bf16x8*)(sBu + (wn16 + j) * 512 + lane * 8);
  #pragma unroll
  for (int j = 0; j < 4; ++j) bg[j] = *(const bf16x8*)(sBg + (wn16 + j) * 512 + lane * 8);
  #pragma unroll
  for (int i = 0; i < 4; ++i)
    #pragma unroll
    for (int j = 0; j < 4; ++j) {
      accu[i][j] = __builtin_amdgcn_mfma_f32_16x16x32_bf16(af[i], bu[j], accu[i][j], 0, 0, 0);
      accg[i][j] = __builtin_amdgcn_mfma_f32_16x16x32_bf16(af[i], bg[j], accg[i][j], 0, 0, 0);
    }
}

// proj = x @ Wcat^T : C[8192][512] f32.  BK=64. grid (mb=64, nb=4)
__global__ __launch_bounds__(256, 2) void gemm_proj_kernel(const __hip_bfloat16* __restrict__ A,
    const __hip_bfloat16* __restrict__ Bt, float* __restrict__ C) {
  __shared__ __align__(16) __hip_bfloat16 sA[8192];
  __shared__ __align__(16) __hip_bfloat16 sB[8192];
  int tid = threadIdx.x, mb = blockIdx.x, nb = blockIdx.y;
  int wave = tid >> 6, lane = tid & 63;
  int wm16 = (wave >> 1) * 4, wn16 = (wave & 1) * 4;
  int fr = lane & 15, q4 = (lane >> 4) * 4;
  f32x4 acc[4][4] = {};
  for (int kt = 0; kt < 32; kt += 2) {
    __syncthreads();
    stage_async_frag(A + ((size_t)(mb * 32 + kt) << 12), sA, wave, lane);
    stage_async_frag(A + ((size_t)(mb * 32 + kt + 1) << 12), sA + 4096, wave, lane);
    stage_async_frag(Bt + ((size_t)(nb * 32 + kt) << 12), sB, wave, lane);
    stage_async_frag(Bt + ((size_t)(nb * 32 + kt + 1) << 12), sB + 4096, wave, lane);
    __syncthreads();
    mfma_single(sA, sB, wm16, wn16, lane, acc);
    mfma_single(sA + 4096, sB + 4096, wm16, wn16, lane, acc);
  }
  #pragma unroll
  for (int i = 0; i < 4; ++i)
    #pragma unroll
    for (int j = 0; j < 4; ++j) {
      int row = mb * 128 + (wm16 + i) * 16 + q4;
      int col = nb * 128 + (wn16 + j) * 16 + fr;
      #pragma unroll
      for (int rg = 0; rg < 4; ++rg)
        C[(size_t)(row + rg) * 512 + col] = acc[i][j][rg];
    }
}

// h = (x@W_up) * silu(x@W_gate); hbuf frag layout. BK=64. grid (mb=64, nb=16)
__global__ __launch_bounds__(256, 2) void gemm_upgate_kernel(const __hip_bfloat16* __restrict__ A,
    const __hip_bfloat16* __restrict__ Bt, __hip_bfloat16* __restrict__ hout) {
  __shared__ __align__(16) __hip_bfloat16 sA[8192];
  __shared__ __align__(16) __hip_bfloat16 sBu[8192];
  __shared__ __align__(16) __hip_bfloat16 sBg[8192];
  int tid = threadIdx.x, mb = blockIdx.x, nb = blockIdx.y;
  int wave = tid >> 6, lane = tid & 63;
  int wm16 = (wave >> 1) * 4, wn16 = (wave & 1) * 4;
  int fr = lane & 15, q4 = (lane >> 4) * 4;
  f32x4 accu[4][4] = {}, accg[4][4] = {};
  for (int kt = 0; kt < 32; kt += 2) {
    __syncthreads();
    stage_async_frag(A + ((size_t)(mb * 32 + kt) << 12), sA, wave, lane);
    stage_async_frag(A + ((size_t)(mb * 32 + kt + 1) << 12), sA + 4096, wave, lane);
    stage_async_frag(Bt + ((size_t)(nb * 32 + kt) << 12), sBu, wave, lane);
    stage_async_frag(Bt + ((size_t)(nb * 32 + kt + 1) << 12), sBu + 4096, wave, lane);
    stage_async_frag(Bt + ((size_t)((nb + 16) * 32 + kt) << 12), sBg, wave, lane);
    stage_async_frag(Bt + ((size_t)((nb + 16) * 32 + kt + 1) << 12), sBg + 4096, wave, lane);
    __syncthreads();
    mfma_dual(sA, sBu, sBg, wm16, wn16, lane, accu, accg);
    mfma_dual(sA + 4096, sBu + 4096, sBg + 4096, wm16, wn16, lane, accu, accg);
  }
  #pragma unroll
  for (int i = 0; i < 4; ++i)
    #pragma unroll
    for (int j = 0; j < 4; ++j) {
      int col = nb * 128 + (wn16 + j) * 16 + fr;
      int q = (col >> 3) & 3, e = col & 7;
      size_t base = ((size_t)(mb * 64 + (col >> 5)) << 12) + (wm16 + i) * 512 + q * 128 + e;
      #pragma unroll
      for (int rg = 0; rg < 4; ++rg) {
        float u = accu[i][j][rg], g = accg[i][j][rg];
        float hv = u * g / (1.f + __expf(-g));
        hout[base + (q4 + rg) * 8] = f2bf(hv);
      }
    }
}

// out = h@Wdown^T + Rd@Wrec^T  (frag K=2048 then K=64), f32 out. BK=64. grid (mb=64, nb=8)
__global__ __launch_bounds__(256, 2) void gemm_final_kernel(const __hip_bfloat16* __restrict__ A,
    const __hip_bfloat16* __restrict__ Bt, const __hip_bfloat16* __restrict__ A2,
    const __hip_bfloat16* __restrict__ B2t, float* __restrict__ C) {
  __shared__ __align__(16) __hip_bfloat16 sA[8192];
  __shared__ __align__(16) __hip_bfloat16 sB[8192];
  int tid = threadIdx.x, mb = blockIdx.x, nb = blockIdx.y;
  int wave = tid >> 6, lane = tid & 63;
  int wm16 = (wave >> 1) * 4, wn16 = (wave & 1) * 4;
  int fr = lane & 15, q4 = (lane >> 4) * 4;
  f32x4 acc[4][4] = {};
  for (int kt = 0; kt < 64; kt += 2) {
    __syncthreads();
    stage_async_frag(A + ((size_t)(mb * 64 + kt) << 12), sA, wave, lane);
    stage_async_frag(A + ((size_t)(mb * 64 + kt + 1) << 12), sA + 4096, wave, lane);
    stage_async_frag(Bt + ((size_t)(nb * 64 + kt) << 12), sB, wave, lane);
    stage_async_frag(Bt + ((size_t)(nb * 64 + kt + 1) << 12), sB + 4096, wave, lane);
    __syncthreads();
    mfma_single(sA, sB, wm16, wn16, lane, acc);
    mfma_single(sA + 4096, sB + 4096, wm16, wn16, lane, acc);
  }
  {
    __syncthreads();
    stage_async_frag(A2 + ((size_t)(mb * 2) << 12), sA, wave, lane);
    stage_async_frag(A2 + ((size_t)(mb * 2 + 1) << 12), sA + 4096, wave, lane);
    stage_async_frag(B2t + ((size_t)(nb * 2) << 12), sB, wave, lane);
    stage_async_frag(B2t + ((size_t)(nb * 2 + 1) << 12), sB + 4096, wave, lane);
    __syncthreads();
    mfma_single(sA, sB, wm16, wn16, lane, acc);
    mfma_single(sA + 4096, sB + 4096, wm16, wn16, lane, acc);
  }
  #pragma unroll
  for (int i = 0; i < 4; ++i)
    #pragma unroll
    for (int j = 0; j < 4; ++j) {
      int row = mb * 128 + (wm16 + i) * 16 + q4;
      int col = nb * 128 + (wn16 + j) * 16 + fr;
      #pragma unroll
      for (int rg = 0; rg < 4; ++rg)
        C[(size_t)(row + rg) * Hd + col] = acc[i][j][rg];
    }
}

// ======================= recurrent (chunked gated linear attention) =======================
// chunk C=64. proj row layout: [0]=z_decay, [1..129)=key(r*64+m), [129..257)=value, [257..321)=ql, [321..385)=qr

__global__ __launch_bounds__(256) void scan_chunk_kernel(const float* __restrict__ proj,
    float* __restrict__ Lam, float* __restrict__ udv, float* __restrict__ alpha,
    float* __restrict__ dS) {
  int bc = blockIdx.x, t0 = bc * 64, tid = threadIdx.x;
  __shared__ float d_s[64], ld_s[64], Lam_s[64], u_s[64];
  __shared__ __align__(16) __hip_bfloat16 k_s[128 * 64];
  __shared__ __align__(16) __hip_bfloat16 v_s[128 * 64];
  if (tid < 64) {
    float z = proj[(size_t)(t0 + tid) * 512];
    float dd = 1.f / (1.f + __expf(-z));
    float l = (z >= 0.f) ? -log1pf(__expf(-z)) : (z - log1pf(__expf(z)));
    d_s[tid] = dd; ld_s[tid] = l;
  }
  __syncthreads();
  if (tid == 0) {
    float s = 0.f;
    for (int j = 0; j < 64; ++j) { s += ld_s[j]; Lam_s[j] = s; }
  }
  __syncthreads();
  float Lend = Lam_s[63];
  if (tid < 64) {
    u_s[tid] = (1.f - d_s[tid]) * __expf(Lend - Lam_s[tid]) * 0.5f;  // includes 1/R
    Lam[t0 + tid] = Lam_s[tid];
    udv[t0 + tid] = (1.f - d_s[tid]) * 0.5f;                          // includes 1/R
  }
  if (tid == 0) alpha[bc] = __expf(Lend);
  __syncthreads();
  for (int i = tid; i < 128 * 64; i += 256) {
    int jr = i >> 6, m = i & 63, j = jr >> 1, r = jr & 1;
    const float* rowp = proj + (size_t)(t0 + j) * 512;
    k_s[i] = f2bf(u_s[j] * rowp[1 + r * 64 + m]);
    v_s[i] = f2bf(rowp[129 + r * 64 + m]);
  }
  __syncthreads();
  int m0 = (tid & 15) * 4, n0 = (tid >> 4) * 4;
  float acc[4][4] = {{0.f}};
  for (int jr = 0; jr < 128; ++jr) {
    ushort4 ku = *(const ushort4*)&k_s[jr * 64 + m0];
    ushort4 vu = *(const ushort4*)&v_s[jr * 64 + n0];
    float k0 = bfu2f(ku.x), k1 = bfu2f(ku.y), k2 = bfu2f(ku.z), k3 = bfu2f(ku.w);
    float v0 = bfu2f(vu.x), v1 = bfu2f(vu.y), v2 = bfu2f(vu.z), v3 = bfu2f(vu.w);
    acc[0][0] += k0 * v0; acc[0][1] += k0 * v1; acc[0][2] += k0 * v2; acc[0][3] += k0 * v3;
    acc[1][0] += k1 * v0; acc[1][1] += k1 * v1; acc[1][2] += k1 * v2; acc[1][3] += k1 * v3;
    acc[2][0] += k2 * v0; acc[2][1] += k2 * v1; acc[2][2] += k2 * v2; acc[2][3] += k2 * v3;
    acc[3][0] += k3 * v0; acc[3][1] += k3 * v1; acc[3][2] += k3 * v2; acc[3][3] += k3 * v3;
  }
  float* outp = dS + (size_t)bc * 4096;
  #pragma unroll
  for (int a = 0; a < 4; ++a)
    #pragma unroll
    for (int b2 = 0; b2 < 4; ++b2)
      outp[(m0 + a) * 64 + (n0 + b2)] = acc[a][b2];
}

__global__ __launch_bounds__(256) void scan_cross_kernel(const float* __restrict__ dS,
    const float* __restrict__ alpha, const float* __restrict__ init_state,
    float* __restrict__ Sin) {
  int idx = blockIdx.x * 256 + threadIdx.x;   // 4 batches * 4096 elems
  int b = idx >> 12, e = idx & 4095;
  float s = init_state[e];
  for (int c = 0; c < 32; ++c) {
    int bc = b * 32 + c;
    Sin[(size_t)bc * 4096 + e] = s;
    s = alpha[bc] * s + dS[(size_t)bc * 4096 + e];
  }
}

#define QLD 68

__global__ __launch_bounds__(256) void scan_read_kernel(const float* __restrict__ proj,
    const float* __restrict__ Lam, const float* __restrict__ udv,
    const float* __restrict__ Sin, __hip_bfloat16* __restrict__ Rd) {
  int bc = blockIdx.x, t0 = bc * 64, tid = threadIdx.x;
  __shared__ __align__(16) __hip_bfloat16 ql_s[64 * QLD];
  __shared__ __align__(16) __hip_bfloat16 kv_s[128 * 64];   // K then V
  __shared__ __align__(16) __hip_bfloat16 S_s[64 * 64];
  __shared__ __align__(16) __hip_bfloat16 P_s[128 * 64];    // [jr][t]
  __shared__ float Lam_s[64], ud_s[64], eL_s[64];
  for (int i = tid; i < 64 * 64; i += 256) {
    int t = i >> 6, m = i & 63;
    ql_s[t * QLD + m] = f2bf(proj[(size_t)(t0 + t) * 512 + 257 + m]);
    S_s[i] = f2bf(Sin[(size_t)bc * 4096 + i]);
  }
  for (int i = tid; i < 128 * 64; i += 256) {
    int jr = i >> 6, m = i & 63, j = jr >> 1, r = jr & 1;
    kv_s[i] = f2bf(proj[(size_t)(t0 + j) * 512 + 1 + r * 64 + m]);
  }
  if (tid < 64) {
    float L = Lam[t0 + tid];
    Lam_s[tid] = L; ud_s[tid] = udv[t0 + tid]; eL_s[tid] = __expf(L);
  }
  __syncthreads();
  int tr = (tid & 15) * 4, n0 = (tid >> 4) * 4;
  float acc[4][4] = {{0.f}};
  for (int mb4 = 0; mb4 < 64; mb4 += 4) {
    float sm[4][4];
    #pragma unroll
    for (int mm = 0; mm < 4; ++mm) {
      ushort4 sv = *(const ushort4*)&S_s[(mb4 + mm) * 64 + n0];
      sm[mm][0] = bfu2f(sv.x); sm[mm][1] = bfu2f(sv.y);
      sm[mm][2] = bfu2f(sv.z); sm[mm][3] = bfu2f(sv.w);
    }
    #pragma unroll
    for (int a = 0; a < 4; ++a) {
      ushort4 qa = *(const ushort4*)&ql_s[(tr + a) * QLD + mb4];
      float q0 = bfu2f(qa.x), q1 = bfu2f(qa.y), q2 = bfu2f(qa.z), q3 = bfu2f(qa.w);
      #pragma unroll
      for (int b2 = 0; b2 < 4; ++b2)
        acc[a][b2] += q0 * sm[0][b2] + q1 * sm[1][b2] + q2 * sm[2][b2] + q3 * sm[3][b2];
    }
  }
  #pragma unroll
  for (int a = 0; a < 4; ++a) {
    float e = eL_s[tr + a];
    #pragma unroll
    for (int b2 = 0; b2 < 4; ++b2) acc[a][b2] *= e;
  }
  {
    int jr = tid >> 1, j = jr >> 1, tb = (tid & 1) * 32;
    float dot[32];
    #pragma unroll
    for (int t2 = 0; t2 < 32; ++t2) dot[t2] = 0.f;
    for (int m = 0; m < 64; m += 4) {
      ushort4 kb = *(const ushort4*)&kv_s[jr * 64 + m];
      float k0 = bfu2f(kb.x), k1 = bfu2f(kb.y), k2 = bfu2f(kb.z), k3 = bfu2f(kb.w);
      #pragma unroll
      for (int t2 = 0; t2 < 32; ++t2) {
        ushort4 qa = *(const ushort4*)&ql_s[(tb + t2) * QLD + m];
        dot[t2] += bfu2f(qa.x) * k0 + bfu2f(qa.y) * k1 + bfu2f(qa.z) * k2 + bfu2f(qa.w) * k3;
      }
    }
    #pragma unroll
    for (int t2 = 0; t2 < 32; ++t2) {
      int t = tb + t2;
      float coef = (j <= t) ? ud_s[j] * __expf(Lam_s[t] - Lam_s[j]) : 0.f;
      P_s[jr * 64 + t] = f2bf(dot[t2] * coef);
    }
  }
  __syncthreads();
  for (int i = tid; i < 128 * 64; i += 256) {    // reload V over K
    int jr = i >> 6, m = i & 63, j = jr >> 1, r = jr & 1;
    kv_s[i] = f2bf(proj[(size_t)(t0 + j) * 512 + 129 + r * 64 + m]);
  }
  __syncthreads();
  for (int jr = 0; jr < 128; ++jr) {
    ushort4 pu = *(const ushort4*)&P_s[jr * 64 + tr];
    ushort4 vu = *(const ushort4*)&kv_s[jr * 64 + n0];
    float p0 = bfu2f(pu.x), p1 = bfu2f(pu.y), p2 = bfu2f(pu.z), p3 = bfu2f(pu.w);
    float v0 = bfu2f(vu.x), v1 = bfu2f(vu.y), v2 = bfu2f(vu.z), v3 = bfu2f(vu.w);
    acc[0][0] += p0 * v0; acc[0][1] += p0 * v1; acc[0][2] += p0 * v2; acc[0][3] += p0 * v3;
    acc[1][0] += p1 * v0; acc[1][1] += p1 * v1; acc[1][2] += p1 * v2; acc[1][3] += p1 * v3;
    acc[2][0] += p2 * v0; acc[2][1] += p2 * v1; acc[2][2] += p2 * v2; acc[2][3] += p2 * v3;
    acc[3][0] += p3 * v0; acc[3][1] += p3 * v1; acc[3][2] += p3 * v2; acc[3][3] += p3 * v3;
  }
  // qr gate + silu + store Rd in FRAG layout (RowDim=8192, K=64 -> 2 ktiles)
  #pragma unroll
  for (int a = 0; a < 4; ++a) {
    int row = t0 + tr + a;
    const float* qrp = proj + (size_t)row * 512 + 321;
    int tBase = (row >> 7) * 2, ri = (row >> 4) & 7, rl = row & 15;
    #pragma unroll
    for (int b2 = 0; b2 < 4; ++b2) {
      int n = n0 + b2;
      float rv = acc[a][b2] * qrp[n];
      float sv = rv / (1.f + __expf(-rv));
      size_t idx = ((size_t)(tBase + (n >> 5)) << 12) + ri * 512
                 + (rl + ((n >> 3) & 3) * 16) * 8 + (n & 7);
      Rd[idx] = f2bf(sv);
    }
  }
}

// ======================= launch =======================

extern "C" void kernel_launch(void* const* d_in, const int* in_sizes, int n_in,
                              void* d_out, int out_size, void* d_ws, size_t ws_size,
                              hipStream_t stream) {
  const float* x      = (const float*)d_in[0];
  const float* W_dec  = (const float*)d_in[1];
  const float* W_key  = (const float*)d_in[2];
  const float* W_val  = (const float*)d_in[3];
  const float* W_ql   = (const float*)d_in[4];
  const float* W_qr   = (const float*)d_in[5];
  const float* W_rec  = (const float*)d_in[6];
  const float* W_up   = (const float*)d_in[7];
  const float* W_gate = (const float*)d_in[8];
  const float* W_down = (const float*)d_in[9];
  const float* init_state = (const float*)d_in[10];
  float* out = (float*)d_out;

  char* w = (char*)d_ws;
  auto take = [&](size_t bytes) { char* p = w; w += (bytes + 255) & ~(size_t)255; return p; };
  __hip_bfloat16* x_fb   = (__hip_bfloat16*)take((size_t)BS * Hd * 2);
  __hip_bfloat16* Wcat_f = (__hip_bfloat16*)take((size_t)512 * Hd * 2);
  __hip_bfloat16* Wug_f  = (__hip_bfloat16*)take((size_t)4096 * Hd * 2);
  __hip_bfloat16* Wdn_f  = (__hip_bfloat16*)take((size_t)Hd * LSd * 2);
  __hip_bfloat16* Wrc_f  = (__hip_bfloat16*)take((size_t)Hd * Md * 2);
  float* proj  = (float*)take((size_t)BS * 512 * 4);
  float* Lam   = (float*)take((size_t)BS * 4);
  float* udv   = (float*)take((size_t)BS * 4);
  float* alpha = (float*)take((size_t)128 * 4);
  float* dS    = (float*)take((size_t)128 * 4096 * 4);
  float* Sin   = (float*)take((size_t)128 * 4096 * 4);
  __hip_bfloat16* Rd   = (__hip_bfloat16*)take((size_t)BS * Md * 2);
  __hip_bfloat16* hbuf = (__hip_bfloat16*)take((size_t)BS * LSd * 2);

  conv_frag_kernel<<<4096, 256, 0, stream>>>(x, x_fb);
  prep_wcat_frag_kernel<<<2048, 256, 0, stream>>>(W_dec, W_key, W_val, W_ql, W_qr, Wcat_f);
  transpose_all_kernel<<<1552, 256, 0, stream>>>(W_up, W_gate, W_down, W_rec,
                                                 Wug_f, Wdn_f, Wrc_f);

  gemm_proj_kernel<<<dim3(64, 4), 256, 0, stream>>>(x_fb, Wcat_f, proj);

  scan_chunk_kernel<<<128, 256, 0, stream>>>(proj, Lam, udv, alpha, dS);
  scan_cross_kernel<<<64, 256, 0, stream>>>(dS, alpha, init_state, Sin);
  scan_read_kernel<<<128, 256, 0, stream>>>(proj, Lam, udv, Sin, Rd);

  gemm_upgate_kernel<<<dim3(64, 16), 256, 0, stream>>>(x_fb, Wug_f, hbuf);
  gemm_final_kernel<<<dim3(64, 8), 256, 0, stream>>>(hbuf, Wdn_f, Rd, Wrc_f, out);
}

// Round 5
// 295.212 us; speedup vs baseline: 1.2840x; 1.0218x over previous
//
#include <hip/hip_runtime.h>
#include <hip/hip_bf16.h>

typedef __bf16 bf16x8 __attribute__((ext_vector_type(8)));
typedef float f32x4 __attribute__((ext_vector_type(4)));

#define BS   8192   // B*S rows
#define Hd   1024
#define LSd  2048
#define Md   64

static __device__ __forceinline__ float bfu2f(unsigned short u) {
  return __uint_as_float(((unsigned int)u) << 16);
}
static __device__ __forceinline__ __hip_bfloat16 f2bf(float f) { return __float2bfloat16(f); }

// ===================== fragment-major tiled layout =====================
// Matrix X[RowDim][K] (operand form: both A and "B^T" are [dim128][K]) stored as
// 8KB tiles of 128 rows x 32 k. Within tile: chunk ri=(row>>4)&7 (512 elems),
// lane slot l=(row&15)+16*((k>>3)&3), elem e=k&7.
// flat = tile*4096 + ri*512 + l*8 + e,  tile = (row>>7)*(K>>5) + (k>>5).
// GEMM stages chunk ri with ONE global_load_lds: lane l reads 16B at
// tile_base + ri*512 + l*8 (contiguous 1KB) -> LDS dst + ri*512 + lane*16B
// (contiguous). MFMA fragment read = base + lane*16B (conflict-free, measured 0).

// ======================= merged prep kernel =======================
// blocks [0,4096): x conv to frag; [4096,6144): Wcat frag; [6144,7696): 4 transposes

__global__ __launch_bounds__(256) void prep_all_kernel(
    const float* __restrict__ x,
    const float* __restrict__ Wd, const float* __restrict__ Wk,
    const float* __restrict__ Wv, const float* __restrict__ Wql,
    const float* __restrict__ Wqr,
    const float* __restrict__ Wup, const float* __restrict__ Wgate,
    const float* __restrict__ Wdown, const float* __restrict__ Wrec,
    __hip_bfloat16* __restrict__ x_fb, __hip_bfloat16* __restrict__ Wcat_f,
    __hip_bfloat16* __restrict__ Wug_f, __hip_bfloat16* __restrict__ Wdn_f,
    __hip_bfloat16* __restrict__ Wrc_f) {
  __shared__ float tile[32][129];
  int b = blockIdx.x, tid = threadIdx.x;
  if (b < 4096) {
    // ---- x f32 [8192][1024] -> frag tiles; one wave per 16x32 chunk ----
    int wid = (b * 256 + tid) >> 6;
    int lane = tid & 63;
    int t = wid >> 3, ri = wid & 7;
    int mb = t >> 5, kt = t & 31;
    int row = mb * 128 + ri * 16 + (lane & 15);
    int k = kt * 32 + (lane >> 4) * 8;
    const float* s = x + (size_t)row * 1024 + k;
    float4 f0 = *(const float4*)s;
    float4 f1 = *(const float4*)(s + 4);
    union { unsigned short u8[8]; uint4 v; } o;
    o.u8[0] = __bfloat16_as_ushort(f2bf(f0.x)); o.u8[1] = __bfloat16_as_ushort(f2bf(f0.y));
    o.u8[2] = __bfloat16_as_ushort(f2bf(f0.z)); o.u8[3] = __bfloat16_as_ushort(f2bf(f0.w));
    o.u8[4] = __bfloat16_as_ushort(f2bf(f1.x)); o.u8[5] = __bfloat16_as_ushort(f2bf(f1.y));
    o.u8[6] = __bfloat16_as_ushort(f2bf(f1.z)); o.u8[7] = __bfloat16_as_ushort(f2bf(f1.w));
    *(uint4*)(x_fb + (size_t)wid * 512 + lane * 8) = o.v;
  } else if (b < 6144) {
    // ---- Wcat frag: N=512 (0 decay,1..128 key,129..256 val,257..320 ql,321..384 qr) K=1024
    int i = (b - 4096) * 256 + tid;
    int t = i >> 12, ri = (i >> 9) & 7, l = (i >> 3) & 63, e = i & 7;
    int n = (t >> 5) * 128 + ri * 16 + (l & 15);
    int h = (t & 31) * 32 + (l >> 4) * 8 + e;
    float v = 0.f;
    if (n == 0)        v = Wd[h];
    else if (n < 129)  v = Wk[h * 128 + (n - 1)];
    else if (n < 257)  v = Wv[h * 128 + (n - 129)];
    else if (n < 321)  v = Wql[h * 64 + (n - 257)];
    else if (n < 385)  v = Wqr[h * 64 + (n - 321)];
    Wcat_f[i] = f2bf(v);
  } else {
    // ---- weight transposes: src f32 [Ktot][Nsrc] -> frag B^T[n][k] ----
    int bb = b - 6144;
    const float* src; __hip_bfloat16* dst; int Ktot, Nsrc, n_off, kt, nb;
    if (bb < 512)        { src = Wup;   dst = Wug_f; Ktot = 1024; Nsrc = 2048; n_off = 0;    int r = bb;        kt = r & 31; nb = r >> 5; }
    else if (bb < 1024)  { src = Wgate; dst = Wug_f; Ktot = 1024; Nsrc = 2048; n_off = 2048; int r = bb - 512;  kt = r & 31; nb = r >> 5; }
    else if (bb < 1536)  { src = Wdown; dst = Wdn_f; Ktot = 2048; Nsrc = 1024; n_off = 0;    int r = bb - 1024; kt = r & 63; nb = r >> 6; }
    else                 { src = Wrec;  dst = Wrc_f; Ktot = 64;   Nsrc = 1024; n_off = 0;    int r = bb - 1536; kt = r & 1;  nb = r >> 1; }
    int k0 = kt * 32, n0 = nb * 128;
    int kr = tid >> 3, nc = (tid & 7) * 16;
    const float* s = src + (size_t)(k0 + kr) * Nsrc + n0 + nc;
    #pragma unroll
    for (int u = 0; u < 16; u += 4) {
      float4 f = *(const float4*)(s + u);
      tile[kr][nc + u + 0] = f.x; tile[kr][nc + u + 1] = f.y;
      tile[kr][nc + u + 2] = f.z; tile[kr][nc + u + 3] = f.w;
    }
    __syncthreads();
    int wave = tid >> 6, lane = tid & 63;
    int tIdx = ((n0 + n_off) >> 7) * (Ktot >> 5) + kt;
    __hip_bfloat16* d = dst + ((size_t)tIdx << 12);
    #pragma unroll
    for (int it = 0; it < 2; ++it) {
      int ri = wave * 2 + it;
      int nl = ri * 16 + (lane & 15), kq = (lane >> 4) * 8;
      union { unsigned short u8[8]; uint4 v; } o;
      #pragma unroll
      for (int e = 0; e < 8; ++e)
        o.u8[e] = __bfloat16_as_ushort(f2bf(tile[kq + e][nl]));
      *(uint4*)(d + ri * 512 + lane * 8) = o.v;
    }
  }
}

// ======================= GEMM core =======================

static __device__ __forceinline__ void stage_async_frag(const __hip_bfloat16* __restrict__ tile_src,
    __hip_bfloat16* __restrict__ dst, int wave, int lane) {
  #pragma unroll
  for (int it = 0; it < 2; ++it) {
    int ri = wave * 2 + it;
    __builtin_amdgcn_global_load_lds(
        (const __attribute__((address_space(1))) void*)(tile_src + ri * 512 + lane * 8),
        (__attribute__((address_space(3))) void*)(dst + ri * 512),
        16, 0, 0);
  }
}

static __device__ __forceinline__ void mfma_single(const __hip_bfloat16* sA, const __hip_bfloat16* sB,
    int wm16, int wn16, int lane, f32x4 acc[4][4]) {
  bf16x8 af[4], bg[4];
  #pragma unroll
  for (int i = 0; i < 4; ++i) af[i] = *(const bf16x8*)(sA + (wm16 + i) * 512 + lane * 8);
  #pragma unroll
  for (int j = 0; j < 4; ++j) bg[j] = *(const bf16x8*)(sB + (wn16 + j) * 512 + lane * 8);
  #pragma unroll
  for (int i = 0; i < 4; ++i)
    #pragma unroll
    for (int j = 0; j < 4; ++j)
      acc[i][j] = __builtin_amdgcn_mfma_f32_16x16x32_bf16(af[i], bg[j], acc[i][j], 0, 0, 0);
}

static __device__ __forceinline__ void mfma_dual(const __hip_bfloat16* sA,
    const __hip_bfloat16* sBu, const __hip_bfloat16* sBg,
    int wm16, int wn16, int lane, f32x4 accu[4][4], f32x4 accg[4][4]) {
  bf16x8 af[4], bu[4], bg[4];
  #pragma unroll
  for (int i = 0; i < 4; ++i) af[i] = *(const bf16x8*)(sA + (wm16 + i) * 512 + lane * 8);
  #pragma unroll
  for (int j = 0; j < 4; ++j) bu[j] = *(const bf16x8*)(sBu + (wn16 + j) * 512 + lane * 8);
  #pragma unroll
  for (int j = 0; j < 4; ++j) bg[j] = *(const bf16x8*)(sBg + (wn16 + j) * 512 + lane * 8);
  #pragma unroll
  for (int i = 0; i < 4; ++i)
    #pragma unroll
    for (int j = 0; j < 4; ++j) {
      accu[i][j] = __builtin_amdgcn_mfma_f32_16x16x32_bf16(af[i], bu[j], accu[i][j], 0, 0, 0);
      accg[i][j] = __builtin_amdgcn_mfma_f32_16x16x32_bf16(af[i], bg[j], accg[i][j], 0, 0, 0);
    }
}

// proj = x @ Wcat^T : C[8192][512] f32.  BK=64. grid (mb=64, nb=4)
__global__ __launch_bounds__(256, 2) void gemm_proj_kernel(const __hip_bfloat16* __restrict__ A,
    const __hip_bfloat16* __restrict__ Bt, float* __restrict__ C) {
  __shared__ __align__(16) __hip_bfloat16 sA[8192];
  __shared__ __align__(16) __hip_bfloat16 sB[8192];
  int tid = threadIdx.x, mb = blockIdx.x, nb = blockIdx.y;
  int wave = tid >> 6, lane = tid & 63;
  int wm16 = (wave >> 1) * 4, wn16 = (wave & 1) * 4;
  int fr = lane & 15, q4 = (lane >> 4) * 4;
  f32x4 acc[4][4] = {};
  for (int kt = 0; kt < 32; kt += 2) {
    __syncthreads();
    stage_async_frag(A + ((size_t)(mb * 32 + kt) << 12), sA, wave, lane);
    stage_async_frag(A + ((size_t)(mb * 32 + kt + 1) << 12), sA + 4096, wave, lane);
    stage_async_frag(Bt + ((size_t)(nb * 32 + kt) << 12), sB, wave, lane);
    stage_async_frag(Bt + ((size_t)(nb * 32 + kt + 1) << 12), sB + 4096, wave, lane);
    __syncthreads();
    mfma_single(sA, sB, wm16, wn16, lane, acc);
    mfma_single(sA + 4096, sB + 4096, wm16, wn16, lane, acc);
  }
  #pragma unroll
  for (int i = 0; i < 4; ++i)
    #pragma unroll
    for (int j = 0; j < 4; ++j) {
      int row = mb * 128 + (wm16 + i) * 16 + q4;
      int col = nb * 128 + (wn16 + j) * 16 + fr;
      #pragma unroll
      for (int rg = 0; rg < 4; ++rg)
        C[(size_t)(row + rg) * 512 + col] = acc[i][j][rg];
    }
}

// h = (x@W_up) * silu(x@W_gate); hbuf frag layout. BK=64. grid (mb=64, nb=16)
__global__ __launch_bounds__(256, 2) void gemm_upgate_kernel(const __hip_bfloat16* __restrict__ A,
    const __hip_bfloat16* __restrict__ Bt, __hip_bfloat16* __restrict__ hout) {
  __shared__ __align__(16) __hip_bfloat16 sA[8192];
  __shared__ __align__(16) __hip_bfloat16 sBu[8192];
  __shared__ __align__(16) __hip_bfloat16 sBg[8192];
  int tid = threadIdx.x, mb = blockIdx.x, nb = blockIdx.y;
  int wave = tid >> 6, lane = tid & 63;
  int wm16 = (wave >> 1) * 4, wn16 = (wave & 1) * 4;
  int fr = lane & 15, q4 = (lane >> 4) * 4;
  f32x4 accu[4][4] = {}, accg[4][4] = {};
  for (int kt = 0; kt < 32; kt += 2) {
    __syncthreads();
    stage_async_frag(A + ((size_t)(mb * 32 + kt) << 12), sA, wave, lane);
    stage_async_frag(A + ((size_t)(mb * 32 + kt + 1) << 12), sA + 4096, wave, lane);
    stage_async_frag(Bt + ((size_t)(nb * 32 + kt) << 12), sBu, wave, lane);
    stage_async_frag(Bt + ((size_t)(nb * 32 + kt + 1) << 12), sBu + 4096, wave, lane);
    stage_async_frag(Bt + ((size_t)((nb + 16) * 32 + kt) << 12), sBg, wave, lane);
    stage_async_frag(Bt + ((size_t)((nb + 16) * 32 + kt + 1) << 12), sBg + 4096, wave, lane);
    __syncthreads();
    mfma_dual(sA, sBu, sBg, wm16, wn16, lane, accu, accg);
    mfma_dual(sA + 4096, sBu + 4096, sBg + 4096, wm16, wn16, lane, accu, accg);
  }
  #pragma unroll
  for (int i = 0; i < 4; ++i)
    #pragma unroll
    for (int j = 0; j < 4; ++j) {
      int col = nb * 128 + (wn16 + j) * 16 + fr;
      int q = (col >> 3) & 3, e = col & 7;
      size_t base = ((size_t)(mb * 64 + (col >> 5)) << 12) + (wm16 + i) * 512 + q * 128 + e;
      #pragma unroll
      for (int rg = 0; rg < 4; ++rg) {
        float u = accu[i][j][rg], g = accg[i][j][rg];
        float hv = u * g / (1.f + __expf(-g));
        hout[base + (q4 + rg) * 8] = f2bf(hv);
      }
    }
}

// out = h@Wdown^T + Rd@Wrec^T  (frag K=2048 then K=64), f32 out. BK=64. grid (mb=64, nb=8)
__global__ __launch_bounds__(256, 2) void gemm_final_kernel(const __hip_bfloat16* __restrict__ A,
    const __hip_bfloat16* __restrict__ Bt, const __hip_bfloat16* __restrict__ A2,
    const __hip_bfloat16* __restrict__ B2t, float* __restrict__ C) {
  __shared__ __align__(16) __hip_bfloat16 sA[8192];
  __shared__ __align__(16) __hip_bfloat16 sB[8192];
  int tid = threadIdx.x, mb = blockIdx.x, nb = blockIdx.y;
  int wave = tid >> 6, lane = tid & 63;
  int wm16 = (wave >> 1) * 4, wn16 = (wave & 1) * 4;
  int fr = lane & 15, q4 = (lane >> 4) * 4;
  f32x4 acc[4][4] = {};
  for (int kt = 0; kt < 64; kt += 2) {
    __syncthreads();
    stage_async_frag(A + ((size_t)(mb * 64 + kt) << 12), sA, wave, lane);
    stage_async_frag(A + ((size_t)(mb * 64 + kt + 1) << 12), sA + 4096, wave, lane);
    stage_async_frag(Bt + ((size_t)(nb * 64 + kt) << 12), sB, wave, lane);
    stage_async_frag(Bt + ((size_t)(nb * 64 + kt + 1) << 12), sB + 4096, wave, lane);
    __syncthreads();
    mfma_single(sA, sB, wm16, wn16, lane, acc);
    mfma_single(sA + 4096, sB + 4096, wm16, wn16, lane, acc);
  }
  {
    __syncthreads();
    stage_async_frag(A2 + ((size_t)(mb * 2) << 12), sA, wave, lane);
    stage_async_frag(A2 + ((size_t)(mb * 2 + 1) << 12), sA + 4096, wave, lane);
    stage_async_frag(B2t + ((size_t)(nb * 2) << 12), sB, wave, lane);
    stage_async_frag(B2t + ((size_t)(nb * 2 + 1) << 12), sB + 4096, wave, lane);
    __syncthreads();
    mfma_single(sA, sB, wm16, wn16, lane, acc);
    mfma_single(sA + 4096, sB + 4096, wm16, wn16, lane, acc);
  }
  #pragma unroll
  for (int i = 0; i < 4; ++i)
    #pragma unroll
    for (int j = 0; j < 4; ++j) {
      int row = mb * 128 + (wm16 + i) * 16 + q4;
      int col = nb * 128 + (wn16 + j) * 16 + fr;
      #pragma unroll
      for (int rg = 0; rg < 4; ++rg)
        C[(size_t)(row + rg) * Hd + col] = acc[i][j][rg];
    }
}

// ======================= recurrent (chunked gated linear attention) =======================
// chunk C=64. proj row layout: [0]=z_decay, [1..129)=key(r*64+m), [129..257)=value, [257..321)=ql, [321..385)=qr

__global__ __launch_bounds__(256) void scan_chunk_kernel(const float* __restrict__ proj,
    float* __restrict__ Lam, float* __restrict__ udv, float* __restrict__ alpha,
    float* __restrict__ dS) {
  int bc = blockIdx.x, t0 = bc * 64, tid = threadIdx.x;
  __shared__ float Lam_s[64], u_s[64];
  __shared__ __align__(16) __hip_bfloat16 k_s[128 * 64];
  __shared__ __align__(16) __hip_bfloat16 v_s[128 * 64];
  float dd = 0.f, v = 0.f;
  if (tid < 64) {
    float z = proj[(size_t)(t0 + tid) * 512];
    dd = 1.f / (1.f + __expf(-z));
    float l = (z >= 0.f) ? -log1pf(__expf(-z)) : (z - log1pf(__expf(z)));
    // wave-64 inclusive prefix sum of l
    v = l;
    #pragma unroll
    for (int off = 1; off < 64; off <<= 1) {
      float o = __shfl_up(v, off, 64);
      if (tid >= off) v += o;
    }
    Lam_s[tid] = v;
    Lam[t0 + tid] = v;
    udv[t0 + tid] = (1.f - dd) * 0.5f;          // includes 1/R
    if (tid == 63) alpha[bc] = __expf(v);
  }
  __syncthreads();
  float Lend = Lam_s[63];
  if (tid < 64) u_s[tid] = (1.f - dd) * __expf(Lend - v) * 0.5f;  // includes 1/R
  __syncthreads();
  for (int i = tid; i < 128 * 64; i += 256) {
    int jr = i >> 6, m = i & 63, j = jr >> 1, r = jr & 1;
    const float* rowp = proj + (size_t)(t0 + j) * 512;
    k_s[i] = f2bf(u_s[j] * rowp[1 + r * 64 + m]);
    v_s[i] = f2bf(rowp[129 + r * 64 + m]);
  }
  __syncthreads();
  int m0 = (tid & 15) * 4, n0 = (tid >> 4) * 4;
  float acc[4][4] = {{0.f}};
  for (int jr = 0; jr < 128; ++jr) {
    ushort4 ku = *(const ushort4*)&k_s[jr * 64 + m0];
    ushort4 vu = *(const ushort4*)&v_s[jr * 64 + n0];
    float k0 = bfu2f(ku.x), k1 = bfu2f(ku.y), k2 = bfu2f(ku.z), k3 = bfu2f(ku.w);
    float v0 = bfu2f(vu.x), v1 = bfu2f(vu.y), v2 = bfu2f(vu.z), v3 = bfu2f(vu.w);
    acc[0][0] += k0 * v0; acc[0][1] += k0 * v1; acc[0][2] += k0 * v2; acc[0][3] += k0 * v3;
    acc[1][0] += k1 * v0; acc[1][1] += k1 * v1; acc[1][2] += k1 * v2; acc[1][3] += k1 * v3;
    acc[2][0] += k2 * v0; acc[2][1] += k2 * v1; acc[2][2] += k2 * v2; acc[2][3] += k2 * v3;
    acc[3][0] += k3 * v0; acc[3][1] += k3 * v1; acc[3][2] += k3 * v2; acc[3][3] += k3 * v3;
  }
  float* outp = dS + (size_t)bc * 4096;
  #pragma unroll
  for (int a = 0; a < 4; ++a)
    #pragma unroll
    for (int b2 = 0; b2 < 4; ++b2)
      outp[(m0 + a) * 64 + (n0 + b2)] = acc[a][b2];
}

#define QLD 68

// scan_read now also reconstructs S_in from dS/alpha (scan_cross folded in)
__global__ __launch_bounds__(256) void scan_read_kernel(const float* __restrict__ proj,
    const float* __restrict__ Lam, const float* __restrict__ udv,
    const float* __restrict__ dS, const float* __restrict__ alpha,
    const float* __restrict__ init_state, __hip_bfloat16* __restrict__ Rd) {
  int bc = blockIdx.x, t0 = bc * 64, tid = threadIdx.x;
  __shared__ __align__(16) __hip_bfloat16 ql_s[64 * QLD];
  __shared__ __align__(16) __hip_bfloat16 kv_s[128 * 64];   // K then V
  __shared__ __align__(16) __hip_bfloat16 S_s[64 * 64];
  __shared__ __align__(16) __hip_bfloat16 P_s[128 * 64];    // [jr][t]
  __shared__ float Lam_s[64], ud_s[64], eL_s[64];
  // ---- cross-chunk scan: S_in = fold of dS/alpha over chunks < c (this batch) ----
  {
    int b = bc >> 5, c = bc & 31;
    float sreg[16];
    #pragma unroll
    for (int k = 0; k < 16; ++k) sreg[k] = init_state[tid + k * 256];
    for (int cp = 0; cp < c; ++cp) {
      float a = alpha[b * 32 + cp];
      const float* dsp = dS + (size_t)(b * 32 + cp) * 4096;
      #pragma unroll
      for (int k = 0; k < 16; ++k) sreg[k] = a * sreg[k] + dsp[tid + k * 256];
    }
    #pragma unroll
    for (int k = 0; k < 16; ++k) S_s[tid + k * 256] = f2bf(sreg[k]);
  }
  for (int i = tid; i < 64 * 64; i += 256) {
    int t = i >> 6, m = i & 63;
    ql_s[t * QLD + m] = f2bf(proj[(size_t)(t0 + t) * 512 + 257 + m]);
  }
  for (int i = tid; i < 128 * 64; i += 256) {
    int jr = i >> 6, m = i & 63, j = jr >> 1, r = jr & 1;
    kv_s[i] = f2bf(proj[(size_t)(t0 + j) * 512 + 1 + r * 64 + m]);
  }
  if (tid < 64) {
    float L = Lam[t0 + tid];
    Lam_s[tid] = L; ud_s[tid] = udv[t0 + tid]; eL_s[tid] = __expf(L);
  }
  __syncthreads();
  int tr = (tid & 15) * 4, n0 = (tid >> 4) * 4;
  float acc[4][4] = {{0.f}};
  // cross term: e^{Lam_t} * (ql_t @ S_in)
  for (int mb4 = 0; mb4 < 64; mb4 += 4) {
    float sm[4][4];
    #pragma unroll
    for (int mm = 0; mm < 4; ++mm) {
      ushort4 sv = *(const ushort4*)&S_s[(mb4 + mm) * 64 + n0];
      sm[mm][0] = bfu2f(sv.x); sm[mm][1] = bfu2f(sv.y);
      sm[mm][2] = bfu2f(sv.z); sm[mm][3] = bfu2f(sv.w);
    }
    #pragma unroll
    for (int a = 0; a < 4; ++a) {
      ushort4 qa = *(const ushort4*)&ql_s[(tr + a) * QLD + mb4];
      float q0 = bfu2f(qa.x), q1 = bfu2f(qa.y), q2 = bfu2f(qa.z), q3 = bfu2f(qa.w);
      #pragma unroll
      for (int b2 = 0; b2 < 4; ++b2)
        acc[a][b2] += q0 * sm[0][b2] + q1 * sm[1][b2] + q2 * sm[2][b2] + q3 * sm[3][b2];
    }
  }
  #pragma unroll
  for (int a = 0; a < 4; ++a) {
    float e = eL_s[tr + a];
    #pragma unroll
    for (int b2 = 0; b2 < 4; ++b2) acc[a][b2] *= e;
  }
  // intra-chunk scores P[jr][t]
  {
    int jr = tid >> 1, j = jr >> 1, tb = (tid & 1) * 32;
    float dot[32];
    #pragma unroll
    for (int t2 = 0; t2 < 32; ++t2) dot[t2] = 0.f;
    for (int m = 0; m < 64; m += 4) {
      ushort4 kb = *(const ushort4*)&kv_s[jr * 64 + m];
      float k0 = bfu2f(kb.x), k1 = bfu2f(kb.y), k2 = bfu2f(kb.z), k3 = bfu2f(kb.w);
      #pragma unroll
      for (int t2 = 0; t2 < 32; ++t2) {
        ushort4 qa = *(const ushort4*)&ql_s[(tb + t2) * QLD + m];
        dot[t2] += bfu2f(qa.x) * k0 + bfu2f(qa.y) * k1 + bfu2f(qa.z) * k2 + bfu2f(qa.w) * k3;
      }
    }
    #pragma unroll
    for (int t2 = 0; t2 < 32; ++t2) {
      int t = tb + t2;
      float coef = (j <= t) ? ud_s[j] * __expf(Lam_s[t] - Lam_s[j]) : 0.f;
      P_s[jr * 64 + t] = f2bf(dot[t2] * coef);
    }
  }
  __syncthreads();
  for (int i = tid; i < 128 * 64; i += 256) {    // reload V over K
    int jr = i >> 6, m = i & 63, j = jr >> 1, r = jr & 1;
    kv_s[i] = f2bf(proj[(size_t)(t0 + j) * 512 + 129 + r * 64 + m]);
  }
  __syncthreads();
  for (int jr = 0; jr < 128; ++jr) {
    ushort4 pu = *(const ushort4*)&P_s[jr * 64 + tr];
    ushort4 vu = *(const ushort4*)&kv_s[jr * 64 + n0];
    float p0 = bfu2f(pu.x), p1 = bfu2f(pu.y), p2 = bfu2f(pu.z), p3 = bfu2f(pu.w);
    float v0 = bfu2f(vu.x), v1 = bfu2f(vu.y), v2 = bfu2f(vu.z), v3 = bfu2f(vu.w);
    acc[0][0] += p0 * v0; acc[0][1] += p0 * v1; acc[0][2] += p0 * v2; acc[0][3] += p0 * v3;
    acc[1][0] += p1 * v0; acc[1][1] += p1 * v1; acc[1][2] += p1 * v2; acc[1][3] += p1 * v3;
    acc[2][0] += p2 * v0; acc[2][1] += p2 * v1; acc[2][2] += p2 * v2; acc[2][3] += p2 * v3;
    acc[3][0] += p3 * v0; acc[3][1] += p3 * v1; acc[3][2] += p3 * v2; acc[3][3] += p3 * v3;
  }
  // qr gate + silu + store Rd in FRAG layout (RowDim=8192, K=64 -> 2 ktiles)
  #pragma unroll
  for (int a = 0; a < 4; ++a) {
    int row = t0 + tr + a;
    const float* qrp = proj + (size_t)row * 512 + 321;
    int tBase = (row >> 7) * 2, ri = (row >> 4) & 7, rl = row & 15;
    #pragma unroll
    for (int b2 = 0; b2 < 4; ++b2) {
      int n = n0 + b2;
      float rv = acc[a][b2] * qrp[n];
      float sv = rv / (1.f + __expf(-rv));
      size_t idx = ((size_t)(tBase + (n >> 5)) << 12) + ri * 512
                 + (rl + ((n >> 3) & 3) * 16) * 8 + (n & 7);
      Rd[idx] = f2bf(sv);
    }
  }
}

// ======================= launch =======================

extern "C" void kernel_launch(void* const* d_in, const int* in_sizes, int n_in,
                              void* d_out, int out_size, void* d_ws, size_t ws_size,
                              hipStream_t stream) {
  const float* x      = (const float*)d_in[0];
  const float* W_dec  = (const float*)d_in[1];
  const float* W_key  = (const float*)d_in[2];
  const float* W_val  = (const float*)d_in[3];
  const float* W_ql   = (const float*)d_in[4];
  const float* W_qr   = (const float*)d_in[5];
  const float* W_rec  = (const float*)d_in[6];
  const float* W_up   = (const float*)d_in[7];
  const float* W_gate = (const float*)d_in[8];
  const float* W_down = (const float*)d_in[9];
  const float* init_state = (const float*)d_in[10];
  float* out = (float*)d_out;

  char* w = (char*)d_ws;
  auto take = [&](size_t bytes) { char* p = w; w += (bytes + 255) & ~(size_t)255; return p; };
  __hip_bfloat16* x_fb   = (__hip_bfloat16*)take((size_t)BS * Hd * 2);
  __hip_bfloat16* Wcat_f = (__hip_bfloat16*)take((size_t)512 * Hd * 2);
  __hip_bfloat16* Wug_f  = (__hip_bfloat16*)take((size_t)4096 * Hd * 2);
  __hip_bfloat16* Wdn_f  = (__hip_bfloat16*)take((size_t)Hd * LSd * 2);
  __hip_bfloat16* Wrc_f  = (__hip_bfloat16*)take((size_t)Hd * Md * 2);
  float* proj  = (float*)take((size_t)BS * 512 * 4);
  float* Lam   = (float*)take((size_t)BS * 4);
  float* udv   = (float*)take((size_t)BS * 4);
  float* alpha = (float*)take((size_t)128 * 4);
  float* dS    = (float*)take((size_t)128 * 4096 * 4);
  __hip_bfloat16* Rd   = (__hip_bfloat16*)take((size_t)BS * Md * 2);
  __hip_bfloat16* hbuf = (__hip_bfloat16*)take((size_t)BS * LSd * 2);

  prep_all_kernel<<<7696, 256, 0, stream>>>(x, W_dec, W_key, W_val, W_ql, W_qr,
                                            W_up, W_gate, W_down, W_rec,
                                            x_fb, Wcat_f, Wug_f, Wdn_f, Wrc_f);

  gemm_proj_kernel<<<dim3(64, 4), 256, 0, stream>>>(x_fb, Wcat_f, proj);

  scan_chunk_kernel<<<128, 256, 0, stream>>>(proj, Lam, udv, alpha, dS);
  scan_read_kernel<<<128, 256, 0, stream>>>(proj, Lam, udv, dS, alpha, init_state, Rd);

  gemm_upgate_kernel<<<dim3(64, 16), 256, 0, stream>>>(x_fb, Wug_f, hbuf);
  gemm_final_kernel<<<dim3(64, 8), 256, 0, stream>>>(hbuf, Wdn_f, Rd, Wrc_f, out);
}